// Round 7
// baseline (3504.567 us; speedup 1.0000x reference)
//
#include <hip/hip_runtime.h>
#include <hip/hip_bf16.h>
#include <math.h>

// Problem constants
#define NN 50000
#define NNP 50048       // rows padded to multiple of BM=64 (and 128)
#define NE 800000
#define DD 256
#define NSTEPS 6

// GEMM tiling: full-width output tile (A read exactly once per GEMM)
#define BM 64
#define BN 256
#define BK 32

typedef unsigned short u16;
typedef _Float16 f16x8 __attribute__((ext_vector_type(8)));
typedef float f32x4 __attribute__((ext_vector_type(4)));

#define MODE_RELU_P  0   // relu(v+b1) -> planes
#define MODE_PLAIN_F 1   // v+b1 -> fp32
#define MODE_RGATE   2   // T = tanh(aux1 + sig(v+b1+b2)*aux2) -> fp32 (in place over aux1)
#define MODE_ZGATE_P 3   // (1-z)*aux1 + z*x(planes) -> planes
#define MODE_ZGATE_F 4   // (1-z)*aux1 + z*x(planes) -> fp32

__device__ __forceinline__ float sigmoidf_(float v) {
    return 1.0f / (1.0f + expf(-v));
}
__device__ __forceinline__ u16 f2h(float v) {
    _Float16 h = (_Float16)v;            // RNE
    u16 u; __builtin_memcpy(&u, &h, 2); return u;
}
__device__ __forceinline__ float h2f(u16 u) {
    _Float16 h; __builtin_memcpy(&h, &u, 2); return (float)h;
}
// fp16 2-way split: v ~= h + l to 2^-22 relative
__device__ __forceinline__ void split2(float v, u16& h, u16& l) {
    h = f2h(v);
    float r = v - h2f(h);
    l = f2h(r);
}
__device__ __forceinline__ unsigned pk(u16 a, u16 b) {
    return (unsigned)a | ((unsigned)b << 16);
}
__device__ __forceinline__ void store_planes(u16* base, size_t ps, size_t off, float v) {
    u16 h, l; split2(v, h, l);
    base[off] = h; base[ps + off] = l;
}
__device__ __forceinline__ void gload16(const void* g, void* l) {
    __builtin_amdgcn_global_load_lds(
        (const __attribute__((address_space(1))) void*)g,
        (__attribute__((address_space(3))) void*)l, 16, 0, 0);
}

// ---------------- CSR build (verified R1-R6) ----------------

__global__ void zero_kernel(int* __restrict__ p, int n) {
    int i = blockIdx.x * blockDim.x + threadIdx.x;
    if (i < n) p[i] = 0;
}
__global__ void hist_kernel(const int* __restrict__ dst, int* __restrict__ counts, int E) {
    int e = blockIdx.x * blockDim.x + threadIdx.x;
    if (e < E) atomicAdd(&counts[dst[e]], 1);
}
__global__ void scan_kernel(const int* __restrict__ counts, int* __restrict__ row_ptr, int n) {
    __shared__ int buf[1024];
    __shared__ int carry;
    const int tid = threadIdx.x;
    if (tid == 0) carry = 0;
    __syncthreads();
    for (int base = 0; base < n; base += 1024) {
        int i = base + tid;
        int v = (i < n) ? counts[i] : 0;
        buf[tid] = v;
        __syncthreads();
        for (int off = 1; off < 1024; off <<= 1) {
            int t = (tid >= off) ? buf[tid - off] : 0;
            __syncthreads();
            buf[tid] += t;
            __syncthreads();
        }
        if (i < n) row_ptr[i] = carry + buf[tid] - v;
        __syncthreads();
        if (tid == 0) carry += buf[1023];
        __syncthreads();
    }
    if (threadIdx.x == 0) row_ptr[n] = carry;
}
__global__ void fill_kernel(const int* __restrict__ src, const int* __restrict__ dst,
                            const int* __restrict__ row_ptr, int* __restrict__ cursor,
                            int* __restrict__ csr_src, int E) {
    int e = blockIdx.x * blockDim.x + threadIdx.x;
    if (e < E) {
        int d = dst[e];
        int p = atomicAdd(&cursor[d], 1);
        csr_src[row_ptr[d] + p] = src[e];
    }
}

// ---------------- fp32 -> 2 fp16 planes (rows padded w/ zero) ----------------
__global__ void split_rows(const float* __restrict__ src, u16* __restrict__ dst,
                           size_t pstride, int srcRows) {
    int row = blockIdx.x;
    int col = threadIdx.x;
    size_t off = (size_t)row * DD + col;
    float v = (row < srcRows) ? src[off] : 0.0f;
    store_planes(dst, pstride, off, v);
}

// ---------------- split-plane fp16 MFMA GEMM, full-width BN=256 ----------------
// C = epilogue(A @ W^T + bias). A,B as 2 fp16 planes (hi/lo), plane-major.
// Dual-K (K=512): k<256 from (pA1,pB1), k>=256 from (pA2,pB2).
// 3-term product (hh, hl, lh) == fp32-grade (2^-22) precision.
// Block = 64 rows x all 256 cols (wave wv owns cols [wv*64, wv*64+64)): A is
// read from HBM exactly once per GEMM. B (weights) is L2-resident.
// LDS staged via global_load_lds with the R4-verified chunk-XOR swizzle
// (0 bank conflicts measured).
template <int MODE>
__global__ __launch_bounds__(256, 3)
void gemm_planes(const u16* __restrict__ pA1, const u16* __restrict__ pA2, size_t psA,
                 const u16* __restrict__ pB1, const u16* __restrict__ pB2, size_t psB,
                 const float* __restrict__ bias1, const float* __restrict__ bias2,
                 const float* __restrict__ aux1, const float* __restrict__ aux2,
                 const u16* __restrict__ auxXp, size_t psX,
                 float* __restrict__ outF, u16* __restrict__ outP, size_t psO,
                 int M, int K) {
    // A: 2 planes x [64][32] at 0 / 2048 ; B: 2 planes x [256][32] at 4096 / 12288
    __shared__ u16 lds[20480];   // 40 KB

    const int tid = threadIdx.x;
    const int lane = tid & 63;
    const int wv = tid >> 6;           // wave 0..3 -> col block wv*64
    const int frow = lane & 15;
    const int kg = lane >> 4;
    const int rowBase = blockIdx.x * BM;

    // staging plan: 40 x 1KB wave-issues per block, 10 per wave.
    // q = wv*10+j; q<8: A (plane q>>2, sub q&3); q>=8: B (qb=q-8: plane qb>>4, sub qb&15)
    int offj[10]; int ldsj[10]; bool isBj[10];
#pragma unroll
    for (int j = 0; j < 10; ++j) {
        int q = wv * 10 + j;
        bool isB = q >= 8;
        int row, plane, ldso;
        if (!isB) {
            plane = q >> 2; int sub = q & 3;
            row = sub * 16 + (lane >> 2);
            ldso = q * 512;
        } else {
            int qb = q - 8;
            plane = qb >> 4; int sub = qb & 15;
            row = sub * 16 + (lane >> 2);
            ldso = 4096 + qb * 512;
        }
        int chunk = (lane & 3) ^ ((row >> 1) & 3);
        int ps = isB ? (int)psB : (int)psA;
        int grow = isB ? row : (rowBase + row);
        offj[j] = plane * ps + grow * DD + chunk * 8;
        ldsj[j] = ldso;
        isBj[j] = isB;
    }

    f32x4 acc[4][4] = {};

    for (int k0 = 0; k0 < K; k0 += BK) {
        const u16* Ab; const u16* Bb; int kc;
        if (k0 < DD) { Ab = pA1; Bb = pB1; kc = k0; }
        else         { Ab = pA2; Bb = pB2; kc = k0 - DD; }

#pragma unroll
        for (int j = 0; j < 10; ++j)
            gload16((isBj[j] ? Bb : Ab) + offj[j] + kc, &lds[ldsj[j]]);
        __syncthreads();

        f16x8 af[2][4];
#pragma unroll
        for (int mf = 0; mf < 4; ++mf) {
            int row = mf * 16 + frow;
            int off = row * 32 + ((kg ^ ((row >> 1) & 3)) * 8);
            af[0][mf] = *reinterpret_cast<const f16x8*>(&lds[off]);
            af[1][mf] = *reinterpret_cast<const f16x8*>(&lds[2048 + off]);
        }
#pragma unroll
        for (int nf = 0; nf < 4; ++nf) {
            int brow = wv * 64 + nf * 16 + frow;
            int boff = 4096 + brow * 32 + ((kg ^ ((brow >> 1) & 3)) * 8);
            f16x8 bh = *reinterpret_cast<const f16x8*>(&lds[boff]);
            f16x8 bl = *reinterpret_cast<const f16x8*>(&lds[boff + 8192]);
#pragma unroll
            for (int mf = 0; mf < 4; ++mf) {
                f32x4 c = acc[mf][nf];
                c = __builtin_amdgcn_mfma_f32_16x16x32_f16(af[0][mf], bh, c, 0, 0, 0);
                c = __builtin_amdgcn_mfma_f32_16x16x32_f16(af[0][mf], bl, c, 0, 0, 0);
                c = __builtin_amdgcn_mfma_f32_16x16x32_f16(af[1][mf], bh, c, 0, 0, 0);
                acc[mf][nf] = c;
            }
        }
        __syncthreads();
    }

    // epilogue
#pragma unroll
    for (int nf = 0; nf < 4; ++nf) {
        int gc = wv * 64 + nf * 16 + frow;
        float b1v = bias1[gc];
        float b2v = 0.0f;
        if (MODE == MODE_RGATE || MODE == MODE_ZGATE_P || MODE == MODE_ZGATE_F)
            b2v = bias2[gc];
#pragma unroll
        for (int mf = 0; mf < 4; ++mf) {
            f32x4 a = acc[mf][nf];
#pragma unroll
            for (int j = 0; j < 4; ++j) {
                int gr = rowBase + mf * 16 + kg * 4 + j;
                if (gr < M) {
                    float v = a[j] + b1v + b2v;
                    size_t off = (size_t)gr * DD + gc;
                    if (MODE == MODE_RELU_P) {
                        store_planes(outP, psO, off, fmaxf(v, 0.0f));
                    } else if (MODE == MODE_PLAIN_F) {
                        outF[off] = v;
                    } else if (MODE == MODE_RGATE) {
                        float r = sigmoidf_(v);
                        outF[off] = tanhf(aux1[off] + r * aux2[off]);
                    } else { // ZGATE
                        float z = sigmoidf_(v);
                        float x = h2f(auxXp[off]) + h2f(auxXp[psX + off]);
                        float o = (1.0f - z) * aux1[off] + z * x;
                        if (MODE == MODE_ZGATE_P) store_planes(outP, psO, off, o);
                        else                      outF[off] = o;
                    }
                }
            }
        }
    }
}

// ---------------- segment sum (gather over CSR) -> msg planes ----------------
__global__ __launch_bounds__(256)
void segsum_kernel(const float* __restrict__ h, const int* __restrict__ row_ptr,
                   const int* __restrict__ csr_src, u16* __restrict__ msgP,
                   size_t ps, int n) {
    int node = blockIdx.x * 4 + threadIdx.y;
    if (node >= n) return;
    int d4 = threadIdx.x * 4;
    int s = row_ptr[node];
    int e = row_ptr[node + 1];
    float4 acc = make_float4(0.f, 0.f, 0.f, 0.f);
    for (int j = s; j < e; ++j) {
        int sn = csr_src[j];
        float4 v = *reinterpret_cast<const float4*>(&h[(size_t)sn * DD + d4]);
        acc.x += v.x; acc.y += v.y; acc.z += v.z; acc.w += v.w;
    }
    size_t off = (size_t)node * DD + d4;
    u16 h0,l0,h1,l1,h2,l2,h3,l3;
    split2(acc.x, h0,l0); split2(acc.y, h1,l1);
    split2(acc.z, h2,l2); split2(acc.w, h3,l3);
    *reinterpret_cast<uint2*>(&msgP[off])      = make_uint2(pk(h0,h1), pk(h2,h3));
    *reinterpret_cast<uint2*>(&msgP[ps + off]) = make_uint2(pk(l0,l1), pk(l2,l3));
}

// ---------------- launch ----------------

extern "C" void kernel_launch(void* const* d_in, const int* in_sizes, int n_in,
                              void* d_out, int out_size, void* d_ws, size_t ws_size,
                              hipStream_t stream) {
    const float* x0  = (const float*)d_in[0];
    const float* W1  = (const float*)d_in[1];
    const float* b1  = (const float*)d_in[2];
    const float* W2  = (const float*)d_in[3];
    const float* b2  = (const float*)d_in[4];
    const float* Wih = (const float*)d_in[5];
    const float* bih = (const float*)d_in[6];
    const float* Whh = (const float*)d_in[7];
    const float* bhh = (const float*)d_in[8];
    const int*   src = (const int*)d_in[9];
    const int*   dst = (const int*)d_in[10];

    // workspace layout (~211.3 MB — R4-proven footprint)
    char* ws = (char*)d_ws;
    const size_t PSA = (size_t)NNP * DD;              // elems per activation plane
    const size_t SP  = PSA * 2 * sizeof(u16);         // 51.25 MB (2 fp16 planes)
    const size_t NB  = PSA * sizeof(float);           // 51.25 MB
    const size_t PSW2 = (size_t)DD * DD;              // 65536
    const size_t PSW3 = (size_t)3 * DD * DD;          // 196608
    u16* XP0   = (u16*)(ws);                          // x planes (even steps)
    u16* XP1   = (u16*)(ws + SP);                     // x planes (odd steps)
    u16* TP    = (u16*)(ws + 2 * SP);                 // t1 planes, then msg planes
    float* F1  = (float*)(ws + 3 * SP);               // h / Gxn / T fp32
    u16* W1P   = (u16*)(ws + 3 * SP + NB);
    u16* W2P   = W1P + 2 * PSW2;
    u16* WIHP  = W2P + 2 * PSW2;
    u16* WHHP  = WIHP + 2 * PSW3;
    int* counts  = (int*)(WHHP + 2 * PSW3);
    int* cursor  = counts + NN;
    int* row_ptr = cursor + NN;                       // NN+1 ints
    int* csr     = row_ptr + NN + 8;                  // NE ints
    const size_t needed = 3 * SP + NB + (4 * PSW2 + 4 * PSW3) * sizeof(u16)
                        + (size_t)(2 * NN + NN + 9 + NE) * sizeof(int);
    if (ws_size < needed) return;   // clean fail instead of OOB crash

    float* FOUT = (float*)d_out;    // scratch: Ghn fp32 each step; final ZGATE_F = answer

    // CSR build
    zero_kernel<<<(2 * NN + 255) / 256, 256, 0, stream>>>(counts, 2 * NN);
    hist_kernel<<<(NE + 255) / 256, 256, 0, stream>>>(dst, counts, NE);
    scan_kernel<<<1, 1024, 0, stream>>>(counts, row_ptr, NN);
    fill_kernel<<<(NE + 255) / 256, 256, 0, stream>>>(src, dst, row_ptr, cursor, csr, NE);

    // pre-split weights (once) and x0 -> XP0
    split_rows<<<DD, 256, 0, stream>>>(W1, W1P, PSW2, DD);
    split_rows<<<DD, 256, 0, stream>>>(W2, W2P, PSW2, DD);
    split_rows<<<3 * DD, 256, 0, stream>>>(Wih, WIHP, PSW3, 3 * DD);
    split_rows<<<3 * DD, 256, 0, stream>>>(Whh, WHHP, PSW3, 3 * DD);
    split_rows<<<NNP, 256, 0, stream>>>(x0, XP0, PSA, NN);

    const dim3 grid(NNP / BM);   // 782 x 1 (full-width tiles)

    for (int s = 0; s < NSTEPS; ++s) {
        u16* XPc = (s & 1) ? XP1 : XP0;
        u16* XPn = (s & 1) ? XP0 : XP1;

        // t1 = ReLU(x @ W1^T + b1) -> TP planes
        gemm_planes<MODE_RELU_P><<<grid, 256, 0, stream>>>(
            XPc, XPc, PSA, W1P, W1P, PSW2, b1, nullptr,
            nullptr, nullptr, nullptr, 0, nullptr, TP, PSA, NN, 256);
        // h = t1 @ W2^T + b2 -> F1 fp32
        gemm_planes<MODE_PLAIN_F><<<grid, 256, 0, stream>>>(
            TP, TP, PSA, W2P, W2P, PSW2, b2, nullptr,
            nullptr, nullptr, nullptr, 0, F1, nullptr, 0, NN, 256);
        // msg = segment_sum(h[src], dst) -> TP planes (t1 dead)
        segsum_kernel<<<dim3((NN + 3) / 4), dim3(64, 4), 0, stream>>>(
            F1, row_ptr, csr, TP, PSA, NN);
        // Ghn = x @ Whh_n^T + bhh_n -> FOUT (d_out scratch; h in F1 dead after segsum)
        gemm_planes<MODE_PLAIN_F><<<grid, 256, 0, stream>>>(
            XPc, XPc, PSA, WHHP + 512 * DD, WHHP + 512 * DD, PSW3, bhh + 512, nullptr,
            nullptr, nullptr, nullptr, 0, FOUT, nullptr, 0, NN, 256);
        // Gxn = msg @ Wih_n^T + bih_n -> F1
        gemm_planes<MODE_PLAIN_F><<<grid, 256, 0, stream>>>(
            TP, TP, PSA, WIHP + 512 * DD, WIHP + 512 * DD, PSW3, bih + 512, nullptr,
            nullptr, nullptr, nullptr, 0, F1, nullptr, 0, NN, 256);
        // T = tanh(Gxn + r*Ghn), r = sig([msg|x]@[Wih_r|Whh_r]^T + bih_r + bhh_r)
        //   -> F1 in place (per-thread read-modify-write of its own element)
        gemm_planes<MODE_RGATE><<<grid, 256, 0, stream>>>(
            TP, XPc, PSA, WIHP, WHHP, PSW3, bih, bhh,
            F1, FOUT, nullptr, 0, F1, nullptr, 0, NN, 512);
        // x_next = (1-z)*T + z*x, z = sig([msg|x]@[Wih_z|Whh_z]^T + ...)
        //   -> planes XPn (steps 0..4) / fp32 d_out (final step)
        if (s < NSTEPS - 1) {
            gemm_planes<MODE_ZGATE_P><<<grid, 256, 0, stream>>>(
                TP, XPc, PSA, WIHP + 256 * DD, WHHP + 256 * DD, PSW3, bih + 256, bhh + 256,
                F1, nullptr, XPc, PSA, nullptr, XPn, PSA, NN, 512);
        } else {
            gemm_planes<MODE_ZGATE_F><<<grid, 256, 0, stream>>>(
                TP, XPc, PSA, WIHP + 256 * DD, WHHP + 256 * DD, PSW3, bih + 256, bhh + 256,
                F1, nullptr, XPc, PSA, FOUT, nullptr, 0, NN, 512);
        }
    }
}

// Round 8
// 3399.602 us; speedup vs baseline: 1.0309x; 1.0309x over previous
//
#include <hip/hip_runtime.h>
#include <hip/hip_bf16.h>
#include <math.h>

// Problem constants
#define NN 50000
#define NNP 50048       // rows padded to multiple of BM=128
#define NE 800000
#define DD 256
#define NSTEPS 6

// GEMM tiling (R6-proven geometry + 2-phase double-buffered pipeline)
#define BM 128
#define BN 128
#define BK 32

typedef unsigned short u16;
typedef _Float16 f16x8 __attribute__((ext_vector_type(8)));
typedef float f32x4 __attribute__((ext_vector_type(4)));

#define MODE_RELU_P  0   // relu(v+b1) -> planes
#define MODE_PLAIN_F 1   // v+b1 -> fp32
#define MODE_RGATE   2   // T = tanh(aux1 + sig(v+b1+b2)*aux2) -> fp32 (in place over aux1)
#define MODE_ZGATE_P 3   // (1-z)*aux1 + z*x(planes) -> planes
#define MODE_ZGATE_F 4   // (1-z)*aux1 + z*x(planes) -> fp32

__device__ __forceinline__ float sigmoidf_(float v) {
    return 1.0f / (1.0f + expf(-v));
}
__device__ __forceinline__ u16 f2h(float v) {
    _Float16 h = (_Float16)v;            // RNE
    u16 u; __builtin_memcpy(&u, &h, 2); return u;
}
__device__ __forceinline__ float h2f(u16 u) {
    _Float16 h; __builtin_memcpy(&h, &u, 2); return (float)h;
}
// fp16 2-way split: v ~= h + l to 2^-22 relative
__device__ __forceinline__ void split2(float v, u16& h, u16& l) {
    h = f2h(v);
    float r = v - h2f(h);
    l = f2h(r);
}
__device__ __forceinline__ unsigned pk(u16 a, u16 b) {
    return (unsigned)a | ((unsigned)b << 16);
}
__device__ __forceinline__ void store_planes(u16* base, size_t ps, size_t off, float v) {
    u16 h, l; split2(v, h, l);
    base[off] = h; base[ps + off] = l;
}
__device__ __forceinline__ void gload16(const void* g, void* l) {
    __builtin_amdgcn_global_load_lds(
        (const __attribute__((address_space(1))) void*)g,
        (__attribute__((address_space(3))) void*)l, 16, 0, 0);
}

// ---------------- CSR build (verified R1-R7) ----------------

__global__ void zero_kernel(int* __restrict__ p, int n) {
    int i = blockIdx.x * blockDim.x + threadIdx.x;
    if (i < n) p[i] = 0;
}
__global__ void hist_kernel(const int* __restrict__ dst, int* __restrict__ counts, int E) {
    int e = blockIdx.x * blockDim.x + threadIdx.x;
    if (e < E) atomicAdd(&counts[dst[e]], 1);
}
__global__ void scan_kernel(const int* __restrict__ counts, int* __restrict__ row_ptr, int n) {
    __shared__ int buf[1024];
    __shared__ int carry;
    const int tid = threadIdx.x;
    if (tid == 0) carry = 0;
    __syncthreads();
    for (int base = 0; base < n; base += 1024) {
        int i = base + tid;
        int v = (i < n) ? counts[i] : 0;
        buf[tid] = v;
        __syncthreads();
        for (int off = 1; off < 1024; off <<= 1) {
            int t = (tid >= off) ? buf[tid - off] : 0;
            __syncthreads();
            buf[tid] += t;
            __syncthreads();
        }
        if (i < n) row_ptr[i] = carry + buf[tid] - v;
        __syncthreads();
        if (tid == 0) carry += buf[1023];
        __syncthreads();
    }
    if (threadIdx.x == 0) row_ptr[n] = carry;
}
__global__ void fill_kernel(const int* __restrict__ src, const int* __restrict__ dst,
                            const int* __restrict__ row_ptr, int* __restrict__ cursor,
                            int* __restrict__ csr_src, int E) {
    int e = blockIdx.x * blockDim.x + threadIdx.x;
    if (e < E) {
        int d = dst[e];
        int p = atomicAdd(&cursor[d], 1);
        csr_src[row_ptr[d] + p] = src[e];
    }
}

// ---------------- fp32 -> 2 fp16 planes (rows padded w/ zero) ----------------
__global__ void split_rows(const float* __restrict__ src, u16* __restrict__ dst,
                           size_t pstride, int srcRows) {
    int row = blockIdx.x;
    int col = threadIdx.x;
    size_t off = (size_t)row * DD + col;
    float v = (row < srcRows) ? src[off] : 0.0f;
    store_planes(dst, pstride, off, v);
}

// ---------------- split-plane fp16 MFMA GEMM, 2-phase pipelined ----------------
// C = epilogue(A @ W^T + bias). A,B as 2 fp16 planes (hi/lo), plane-major.
// Dual-K (K=512): k<256 from (pA1,pB1), k>=256 from (pA2,pB2).
// 3-term product (hh, hl, lh) == fp32-grade (2^-22) precision.
// Double-buffered LDS (2 x 32KB) with counted vmcnt(8): next tile's
// global_load_lds stay in flight across the barrier, hidden under MFMA.
template <int MODE>
__global__ __launch_bounds__(256, 2)
void gemm_planes(const u16* __restrict__ pA1, const u16* __restrict__ pA2, size_t psA,
                 const u16* __restrict__ pB1, const u16* __restrict__ pB2, size_t psB,
                 const float* __restrict__ bias1, const float* __restrict__ bias2,
                 const float* __restrict__ aux1, const float* __restrict__ aux2,
                 const u16* __restrict__ auxXp, size_t psX,
                 float* __restrict__ outF, u16* __restrict__ outP, size_t psO,
                 int M, int K) {
    // per buffer (16384 u16): A 2 planes x [128][32] at 0/4096; B same at 8192/12288
    __shared__ u16 lds[2][16384];   // 64 KB

    const int tid = threadIdx.x;
    const int lane = tid & 63;
    const int wv = tid >> 6;
    const int wr = wv >> 1;            // wave row 0..1 (64 rows)
    const int wc = wv & 1;             // wave col 0..1 (64 cols)
    const int frow = lane & 15;
    const int kg = lane >> 4;
    const int rowBase = blockIdx.x * BM;
    const int colBase = blockIdx.y * BN;

    // staging plan: 32 x 1KB wave-issues per tile, 8 per wave (R6-verified, 0 conflicts).
    // q = wv*8+j; q<16: A plane (q>>3), sub-tile q&7; q>=16: B plane ((q-16)>>3).
    int offj[8]; int ldsj[8]; bool isBj[8];
#pragma unroll
    for (int j = 0; j < 8; ++j) {
        int q = wv * 8 + j;
        bool isB = q >= 16;
        int p = (q >> 3) & 1;
        int sub = q & 7;
        int row = sub * 16 + (lane >> 2);
        int chunk = (lane & 3) ^ ((row >> 1) & 3);
        int ps = isB ? (int)psB : (int)psA;
        int grow = (isB ? colBase : rowBase) + row;
        offj[j] = p * ps + grow * DD + chunk * 8;
        ldsj[j] = q * 512;
        isBj[j] = isB;
    }

    auto STAGE = [&](int buf, int t) {
        const int k0 = t * BK;
        const u16* Ab; const u16* Bb; int kc;
        if (k0 < DD) { Ab = pA1; Bb = pB1; kc = k0; }
        else         { Ab = pA2; Bb = pB2; kc = k0 - DD; }
#pragma unroll
        for (int j = 0; j < 8; ++j)
            gload16((isBj[j] ? Bb : Ab) + offj[j] + kc, &lds[buf][ldsj[j]]);
    };

    f32x4 acc[4][4] = {};
    const int NT = K / BK;

    STAGE(0, 0);
    for (int t = 0; t < NT; ++t) {
        const int cur = t & 1;
        if (t + 1 < NT) {
            STAGE(cur ^ 1, t + 1);   // issue next tile's loads (stay in flight)
            asm volatile("s_waitcnt vmcnt(8)" ::: "memory");   // only current tile drained
        } else {
            asm volatile("s_waitcnt vmcnt(0)" ::: "memory");
        }
        __builtin_amdgcn_s_barrier();   // lds[cur] ready for all waves

        const u16* L = lds[cur];
        f16x8 af[2][4];
#pragma unroll
        for (int mf = 0; mf < 4; ++mf) {
            int row = wr * 64 + mf * 16 + frow;
            int off = row * 32 + ((kg ^ ((row >> 1) & 3)) * 8);
            af[0][mf] = *reinterpret_cast<const f16x8*>(&L[off]);
            af[1][mf] = *reinterpret_cast<const f16x8*>(&L[4096 + off]);
        }
#pragma unroll
        for (int nf = 0; nf < 4; ++nf) {
            int brow = wc * 64 + nf * 16 + frow;
            int boff = 8192 + brow * 32 + ((kg ^ ((brow >> 1) & 3)) * 8);
            f16x8 bh = *reinterpret_cast<const f16x8*>(&L[boff]);
            f16x8 bl = *reinterpret_cast<const f16x8*>(&L[boff + 4096]);
#pragma unroll
            for (int mf = 0; mf < 4; ++mf) {
                f32x4 c = acc[mf][nf];
                c = __builtin_amdgcn_mfma_f32_16x16x32_f16(af[0][mf], bh, c, 0, 0, 0);
                c = __builtin_amdgcn_mfma_f32_16x16x32_f16(af[0][mf], bl, c, 0, 0, 0);
                c = __builtin_amdgcn_mfma_f32_16x16x32_f16(af[1][mf], bh, c, 0, 0, 0);
                acc[mf][nf] = c;
            }
        }
        __builtin_amdgcn_s_barrier();   // all waves done reading lds[cur]; safe to overwrite
    }

    // epilogue (R6-identical layout)
#pragma unroll
    for (int nf = 0; nf < 4; ++nf) {
        int gc = colBase + wc * 64 + nf * 16 + frow;
        float b1v = bias1[gc];
        float b2v = 0.0f;
        if (MODE == MODE_RGATE || MODE == MODE_ZGATE_P || MODE == MODE_ZGATE_F)
            b2v = bias2[gc];
#pragma unroll
        for (int mf = 0; mf < 4; ++mf) {
            f32x4 a = acc[mf][nf];
#pragma unroll
            for (int j = 0; j < 4; ++j) {
                int gr = rowBase + wr * 64 + mf * 16 + kg * 4 + j;
                if (gr < M) {
                    float v = a[j] + b1v + b2v;
                    size_t off = (size_t)gr * DD + gc;
                    if (MODE == MODE_RELU_P) {
                        store_planes(outP, psO, off, fmaxf(v, 0.0f));
                    } else if (MODE == MODE_PLAIN_F) {
                        outF[off] = v;
                    } else if (MODE == MODE_RGATE) {
                        float r = sigmoidf_(v);
                        outF[off] = tanhf(aux1[off] + r * aux2[off]);
                    } else { // ZGATE
                        float z = sigmoidf_(v);
                        float x = h2f(auxXp[off]) + h2f(auxXp[psX + off]);
                        float o = (1.0f - z) * aux1[off] + z * x;
                        if (MODE == MODE_ZGATE_P) store_planes(outP, psO, off, o);
                        else                      outF[off] = o;
                    }
                }
            }
        }
    }
}

// ---------------- segment sum (gather over CSR) -> msg planes ----------------
__global__ __launch_bounds__(256)
void segsum_kernel(const float* __restrict__ h, const int* __restrict__ row_ptr,
                   const int* __restrict__ csr_src, u16* __restrict__ msgP,
                   size_t ps, int n) {
    int node = blockIdx.x * 4 + threadIdx.y;
    if (node >= n) return;
    int d4 = threadIdx.x * 4;
    int s = row_ptr[node];
    int e = row_ptr[node + 1];
    float4 acc = make_float4(0.f, 0.f, 0.f, 0.f);
    for (int j = s; j < e; ++j) {
        int sn = csr_src[j];
        float4 v = *reinterpret_cast<const float4*>(&h[(size_t)sn * DD + d4]);
        acc.x += v.x; acc.y += v.y; acc.z += v.z; acc.w += v.w;
    }
    size_t off = (size_t)node * DD + d4;
    u16 h0,l0,h1,l1,h2,l2,h3,l3;
    split2(acc.x, h0,l0); split2(acc.y, h1,l1);
    split2(acc.z, h2,l2); split2(acc.w, h3,l3);
    *reinterpret_cast<uint2*>(&msgP[off])      = make_uint2(pk(h0,h1), pk(h2,h3));
    *reinterpret_cast<uint2*>(&msgP[ps + off]) = make_uint2(pk(l0,l1), pk(l2,l3));
}

// ---------------- launch ----------------

extern "C" void kernel_launch(void* const* d_in, const int* in_sizes, int n_in,
                              void* d_out, int out_size, void* d_ws, size_t ws_size,
                              hipStream_t stream) {
    const float* x0  = (const float*)d_in[0];
    const float* W1  = (const float*)d_in[1];
    const float* b1  = (const float*)d_in[2];
    const float* W2  = (const float*)d_in[3];
    const float* b2  = (const float*)d_in[4];
    const float* Wih = (const float*)d_in[5];
    const float* bih = (const float*)d_in[6];
    const float* Whh = (const float*)d_in[7];
    const float* bhh = (const float*)d_in[8];
    const int*   src = (const int*)d_in[9];
    const int*   dst = (const int*)d_in[10];

    // workspace layout (~211.3 MB — R4/R7-proven footprint)
    char* ws = (char*)d_ws;
    const size_t PSA = (size_t)NNP * DD;              // elems per activation plane
    const size_t SP  = PSA * 2 * sizeof(u16);         // 51.25 MB (2 fp16 planes)
    const size_t NB  = PSA * sizeof(float);           // 51.25 MB
    const size_t PSW2 = (size_t)DD * DD;              // 65536
    const size_t PSW3 = (size_t)3 * DD * DD;          // 196608
    u16* XP0   = (u16*)(ws);                          // x planes (even steps)
    u16* XP1   = (u16*)(ws + SP);                     // x planes (odd steps)
    u16* TP    = (u16*)(ws + 2 * SP);                 // t1 planes, then msg planes
    float* F1  = (float*)(ws + 3 * SP);               // h / Gxn / T fp32
    u16* W1P   = (u16*)(ws + 3 * SP + NB);
    u16* W2P   = W1P + 2 * PSW2;
    u16* WIHP  = W2P + 2 * PSW2;
    u16* WHHP  = WIHP + 2 * PSW3;
    int* counts  = (int*)(WHHP + 2 * PSW3);
    int* cursor  = counts + NN;
    int* row_ptr = cursor + NN;                       // NN+1 ints
    int* csr     = row_ptr + NN + 8;                  // NE ints
    const size_t needed = 3 * SP + NB + (4 * PSW2 + 4 * PSW3) * sizeof(u16)
                        + (size_t)(2 * NN + NN + 9 + NE) * sizeof(int);
    if (ws_size < needed) return;   // clean fail instead of OOB crash

    float* FOUT = (float*)d_out;    // scratch: Ghn fp32 each step; final ZGATE_F = answer

    // CSR build
    zero_kernel<<<(2 * NN + 255) / 256, 256, 0, stream>>>(counts, 2 * NN);
    hist_kernel<<<(NE + 255) / 256, 256, 0, stream>>>(dst, counts, NE);
    scan_kernel<<<1, 1024, 0, stream>>>(counts, row_ptr, NN);
    fill_kernel<<<(NE + 255) / 256, 256, 0, stream>>>(src, dst, row_ptr, cursor, csr, NE);

    // pre-split weights (once) and x0 -> XP0
    split_rows<<<DD, 256, 0, stream>>>(W1, W1P, PSW2, DD);
    split_rows<<<DD, 256, 0, stream>>>(W2, W2P, PSW2, DD);
    split_rows<<<3 * DD, 256, 0, stream>>>(Wih, WIHP, PSW3, 3 * DD);
    split_rows<<<3 * DD, 256, 0, stream>>>(Whh, WHHP, PSW3, 3 * DD);
    split_rows<<<NNP, 256, 0, stream>>>(x0, XP0, PSA, NN);

    const dim3 grid(NNP / BM, DD / BN);   // 391 x 2

    for (int s = 0; s < NSTEPS; ++s) {
        u16* XPc = (s & 1) ? XP1 : XP0;
        u16* XPn = (s & 1) ? XP0 : XP1;

        // t1 = ReLU(x @ W1^T + b1) -> TP planes
        gemm_planes<MODE_RELU_P><<<grid, 256, 0, stream>>>(
            XPc, XPc, PSA, W1P, W1P, PSW2, b1, nullptr,
            nullptr, nullptr, nullptr, 0, nullptr, TP, PSA, NN, 256);
        // h = t1 @ W2^T + b2 -> F1 fp32
        gemm_planes<MODE_PLAIN_F><<<grid, 256, 0, stream>>>(
            TP, TP, PSA, W2P, W2P, PSW2, b2, nullptr,
            nullptr, nullptr, nullptr, 0, F1, nullptr, 0, NN, 256);
        // msg = segment_sum(h[src], dst) -> TP planes (t1 dead)
        segsum_kernel<<<dim3((NN + 3) / 4), dim3(64, 4), 0, stream>>>(
            F1, row_ptr, csr, TP, PSA, NN);
        // Ghn = x @ Whh_n^T + bhh_n -> FOUT (d_out scratch; h in F1 dead after segsum)
        gemm_planes<MODE_PLAIN_F><<<grid, 256, 0, stream>>>(
            XPc, XPc, PSA, WHHP + 512 * DD, WHHP + 512 * DD, PSW3, bhh + 512, nullptr,
            nullptr, nullptr, nullptr, 0, FOUT, nullptr, 0, NN, 256);
        // Gxn = msg @ Wih_n^T + bih_n -> F1
        gemm_planes<MODE_PLAIN_F><<<grid, 256, 0, stream>>>(
            TP, TP, PSA, WIHP + 512 * DD, WIHP + 512 * DD, PSW3, bih + 512, nullptr,
            nullptr, nullptr, nullptr, 0, F1, nullptr, 0, NN, 256);
        // T = tanh(Gxn + r*Ghn), r = sig([msg|x]@[Wih_r|Whh_r]^T + bih_r + bhh_r)
        //   -> F1 in place (per-thread read-modify-write of its own element)
        gemm_planes<MODE_RGATE><<<grid, 256, 0, stream>>>(
            TP, XPc, PSA, WIHP, WHHP, PSW3, bih, bhh,
            F1, FOUT, nullptr, 0, F1, nullptr, 0, NN, 512);
        // x_next = (1-z)*T + z*x, z = sig([msg|x]@[Wih_z|Whh_z]^T + ...)
        //   -> planes XPn (steps 0..4) / fp32 d_out (final step)
        if (s < NSTEPS - 1) {
            gemm_planes<MODE_ZGATE_P><<<grid, 256, 0, stream>>>(
                TP, XPc, PSA, WIHP + 256 * DD, WHHP + 256 * DD, PSW3, bih + 256, bhh + 256,
                F1, nullptr, XPc, PSA, nullptr, XPn, PSA, NN, 512);
        } else {
            gemm_planes<MODE_ZGATE_F><<<grid, 256, 0, stream>>>(
                TP, XPc, PSA, WIHP + 256 * DD, WHHP + 256 * DD, PSW3, bih + 256, bhh + 256,
                F1, nullptr, XPc, PSA, FOUT, nullptr, 0, NN, 512);
        }
    }
}

// Round 9
// 2907.466 us; speedup vs baseline: 1.2054x; 1.1693x over previous
//
#include <hip/hip_runtime.h>
#include <hip/hip_bf16.h>
#include <math.h>

// Problem constants
#define NN 50000
#define NNP 50048       // rows padded to multiple of BM=128
#define NE 800000
#define DD 256
#define NSTEPS 6

// GEMM tiling (R6-proven champion geometry)
#define BM 128
#define BN 128
#define BK 32

typedef unsigned short u16;
typedef _Float16 f16x8 __attribute__((ext_vector_type(8)));
typedef float f32x4 __attribute__((ext_vector_type(4)));

#define MODE_RELU_P  0   // relu(v+b1) -> planes
#define MODE_PLAIN_F 1   // v+b1 -> fp32

__device__ __forceinline__ float sigmoidf_(float v) {
    return 1.0f / (1.0f + expf(-v));
}
__device__ __forceinline__ u16 f2h(float v) {
    _Float16 h = (_Float16)v;            // RNE
    u16 u; __builtin_memcpy(&u, &h, 2); return u;
}
__device__ __forceinline__ float h2f(u16 u) {
    _Float16 h; __builtin_memcpy(&h, &u, 2); return (float)h;
}
// fp16 2-way split: v ~= h + l to 2^-22 relative
__device__ __forceinline__ void split2(float v, u16& h, u16& l) {
    h = f2h(v);
    float r = v - h2f(h);
    l = f2h(r);
}
__device__ __forceinline__ unsigned pk(u16 a, u16 b) {
    return (unsigned)a | ((unsigned)b << 16);
}
__device__ __forceinline__ void store_planes(u16* base, size_t ps, size_t off, float v) {
    u16 h, l; split2(v, h, l);
    base[off] = h; base[ps + off] = l;
}
__device__ __forceinline__ void gload16(const void* g, void* l) {
    __builtin_amdgcn_global_load_lds(
        (const __attribute__((address_space(1))) void*)g,
        (__attribute__((address_space(3))) void*)l, 16, 0, 0);
}

// ---------------- CSR build (verified R1-R8) ----------------

__global__ void zero_kernel(int* __restrict__ p, int n) {
    int i = blockIdx.x * blockDim.x + threadIdx.x;
    if (i < n) p[i] = 0;
}
__global__ void hist_kernel(const int* __restrict__ dst, int* __restrict__ counts, int E) {
    int e = blockIdx.x * blockDim.x + threadIdx.x;
    if (e < E) atomicAdd(&counts[dst[e]], 1);
}
__global__ void scan_kernel(const int* __restrict__ counts, int* __restrict__ row_ptr, int n) {
    __shared__ int buf[1024];
    __shared__ int carry;
    const int tid = threadIdx.x;
    if (tid == 0) carry = 0;
    __syncthreads();
    for (int base = 0; base < n; base += 1024) {
        int i = base + tid;
        int v = (i < n) ? counts[i] : 0;
        buf[tid] = v;
        __syncthreads();
        for (int off = 1; off < 1024; off <<= 1) {
            int t = (tid >= off) ? buf[tid - off] : 0;
            __syncthreads();
            buf[tid] += t;
            __syncthreads();
        }
        if (i < n) row_ptr[i] = carry + buf[tid] - v;
        __syncthreads();
        if (tid == 0) carry += buf[1023];
        __syncthreads();
    }
    if (threadIdx.x == 0) row_ptr[n] = carry;
}
__global__ void fill_kernel(const int* __restrict__ src, const int* __restrict__ dst,
                            const int* __restrict__ row_ptr, int* __restrict__ cursor,
                            int* __restrict__ csr_src, int E) {
    int e = blockIdx.x * blockDim.x + threadIdx.x;
    if (e < E) {
        int d = dst[e];
        int p = atomicAdd(&cursor[d], 1);
        csr_src[row_ptr[d] + p] = src[e];
    }
}

// ---------------- fp32 -> 2 fp16 planes (rows padded w/ zero) ----------------
__global__ void split_rows(const float* __restrict__ src, u16* __restrict__ dst,
                           size_t pstride, int srcRows) {
    int row = blockIdx.x;
    int col = threadIdx.x;
    size_t off = (size_t)row * DD + col;
    float v = (row < srcRows) ? src[off] : 0.0f;
    store_planes(dst, pstride, off, v);
}

// ---------------- split-plane fp16 MFMA GEMM (R6 champion, K=256) ----------------
// C = epilogue(A @ W^T + bias). A,B as 2 fp16 planes (hi/lo), plane-major.
// 3-term product (hh, hl, lh) == fp32-grade (2^-22) precision.
template <int MODE>
__global__ __launch_bounds__(256, 4)
void gemm_planes(const u16* __restrict__ pA, size_t psA,
                 const u16* __restrict__ pB, size_t psB,
                 const float* __restrict__ bias1,
                 float* __restrict__ outF, u16* __restrict__ outP, size_t psO,
                 int M) {
    __shared__ u16 lds[16384];   // A: 2 planes x [128][32] = 8192; B same at +8192

    const int tid = threadIdx.x;
    const int lane = tid & 63;
    const int wv = tid >> 6;
    const int wr = wv >> 1;            // wave row 0..1 (64 rows)
    const int wc = wv & 1;             // wave col 0..1 (64 cols)
    const int frow = lane & 15;
    const int kg = lane >> 4;
    const int rowBase = blockIdx.x * BM;
    const int colBase = blockIdx.y * BN;

    // staging plan: 32 x 1KB wave-issues per tile, 8 per wave (0 bank conflicts).
    int offj[8]; int ldsj[8]; bool isBj[8];
#pragma unroll
    for (int j = 0; j < 8; ++j) {
        int q = wv * 8 + j;
        bool isB = q >= 16;
        int p = (q >> 3) & 1;
        int sub = q & 7;
        int row = sub * 16 + (lane >> 2);
        int chunk = (lane & 3) ^ ((row >> 1) & 3);
        int ps = isB ? (int)psB : (int)psA;
        int grow = (isB ? colBase : rowBase) + row;
        offj[j] = p * ps + grow * DD + chunk * 8;
        ldsj[j] = q * 512;
        isBj[j] = isB;
    }

    f32x4 acc[4][4] = {};

    for (int kc = 0; kc < DD; kc += BK) {
#pragma unroll
        for (int j = 0; j < 8; ++j)
            gload16((isBj[j] ? pB : pA) + offj[j] + kc, &lds[ldsj[j]]);
        __syncthreads();

        f16x8 af[2][4];
#pragma unroll
        for (int mf = 0; mf < 4; ++mf) {
            int row = wr * 64 + mf * 16 + frow;
            int off = row * 32 + ((kg ^ ((row >> 1) & 3)) * 8);
            af[0][mf] = *reinterpret_cast<const f16x8*>(&lds[off]);
            af[1][mf] = *reinterpret_cast<const f16x8*>(&lds[4096 + off]);
        }
#pragma unroll
        for (int nf = 0; nf < 4; ++nf) {
            int brow = wc * 64 + nf * 16 + frow;
            int boff = 8192 + brow * 32 + ((kg ^ ((brow >> 1) & 3)) * 8);
            f16x8 bh = *reinterpret_cast<const f16x8*>(&lds[boff]);
            f16x8 bl = *reinterpret_cast<const f16x8*>(&lds[boff + 4096]);
#pragma unroll
            for (int mf = 0; mf < 4; ++mf) {
                f32x4 c = acc[mf][nf];
                c = __builtin_amdgcn_mfma_f32_16x16x32_f16(af[0][mf], bh, c, 0, 0, 0);
                c = __builtin_amdgcn_mfma_f32_16x16x32_f16(af[0][mf], bl, c, 0, 0, 0);
                c = __builtin_amdgcn_mfma_f32_16x16x32_f16(af[1][mf], bh, c, 0, 0, 0);
                acc[mf][nf] = c;
            }
        }
        __syncthreads();
    }

#pragma unroll
    for (int nf = 0; nf < 4; ++nf) {
        int gc = colBase + wc * 64 + nf * 16 + frow;
        float b1v = bias1[gc];
#pragma unroll
        for (int mf = 0; mf < 4; ++mf) {
            f32x4 a = acc[mf][nf];
#pragma unroll
            for (int j = 0; j < 4; ++j) {
                int gr = rowBase + wr * 64 + mf * 16 + kg * 4 + j;
                if (gr < M) {
                    float v = a[j] + b1v;
                    size_t off = (size_t)gr * DD + gc;
                    if (MODE == MODE_RELU_P) store_planes(outP, psO, off, fmaxf(v, 0.0f));
                    else                     outF[off] = v;
                }
            }
        }
    }
}

// ---------------- fused r,z gate GEMM (K=512, 2 gates per A-stage) ----------------
// r = sig([msg|x] @ [Wih_r|Whh_r]^T + bih_r + bhh_r); z likewise with _z rows.
// A staged once per k-iter serves BOTH gate panels: 96 MFMA / 48KB staged.
// Outputs r,z as fp16 into RZ (plane 0 = r, plane 1 = z).
__global__ __launch_bounds__(256, 2)
void gemm_rz(const u16* __restrict__ pA1, const u16* __restrict__ pA2, size_t psA,
             const u16* __restrict__ pB1, const u16* __restrict__ pB2, size_t psB,
             const float* __restrict__ bih, const float* __restrict__ bhh,
             u16* __restrict__ RZ, size_t psRZ, int M) {
    // A: hi 0, lo 4096 | B gate0(r): hi 8192, lo 12288 | gate1(z): hi 16384, lo 20480
    __shared__ u16 lds[24576];   // 48 KB

    const int tid = threadIdx.x;
    const int lane = tid & 63;
    const int wv = tid >> 6;
    const int wr = wv >> 1;
    const int wc = wv & 1;
    const int frow = lane & 15;
    const int kg = lane >> 4;
    const int rowBase = blockIdx.x * BM;
    const int colBase = blockIdx.y * BN;

    // staging: 48 x 1KB wave-issues per tile, 12 per wave.
    int offj[12]; int ldsj[12]; bool isBj[12];
#pragma unroll
    for (int j = 0; j < 12; ++j) {
        int q = wv * 12 + j;
        bool isB = q >= 16;
        int row, ldso, eoff;
        if (!isB) {
            int p = (q >> 3) & 1; int sub = q & 7;
            row = sub * 16 + (lane >> 2);
            int chunk = (lane & 3) ^ ((row >> 1) & 3);
            eoff = p * (int)psA + (rowBase + row) * DD + chunk * 8;
            ldso = q * 512;
        } else {
            int qb = q - 16;                  // 0..31
            int gate = qb >> 4;               // 0=r, 1=z
            int p = (qb >> 3) & 1; int sub = qb & 7;
            row = sub * 16 + (lane >> 2);
            int chunk = (lane & 3) ^ ((row >> 1) & 3);
            eoff = p * (int)psB + (gate * 256 + colBase + row) * DD + chunk * 8;
            ldso = 8192 + qb * 512;
        }
        offj[j] = eoff; ldsj[j] = ldso; isBj[j] = isB;
    }

    f32x4 accg[2][4][4] = {};

    for (int k0 = 0; k0 < 512; k0 += BK) {
        const u16* Ab; const u16* Bb; int kc;
        if (k0 < DD) { Ab = pA1; Bb = pB1; kc = k0; }
        else         { Ab = pA2; Bb = pB2; kc = k0 - DD; }

#pragma unroll
        for (int j = 0; j < 12; ++j)
            gload16((isBj[j] ? Bb : Ab) + offj[j] + kc, &lds[ldsj[j]]);
        __syncthreads();

        f16x8 af[2][4];
#pragma unroll
        for (int mf = 0; mf < 4; ++mf) {
            int row = wr * 64 + mf * 16 + frow;
            int off = row * 32 + ((kg ^ ((row >> 1) & 3)) * 8);
            af[0][mf] = *reinterpret_cast<const f16x8*>(&lds[off]);
            af[1][mf] = *reinterpret_cast<const f16x8*>(&lds[4096 + off]);
        }
#pragma unroll
        for (int g = 0; g < 2; ++g) {
#pragma unroll
            for (int nf = 0; nf < 4; ++nf) {
                int brow = wc * 64 + nf * 16 + frow;
                int boff = 8192 + g * 8192 + brow * 32 + ((kg ^ ((brow >> 1) & 3)) * 8);
                f16x8 bh = *reinterpret_cast<const f16x8*>(&lds[boff]);
                f16x8 bl = *reinterpret_cast<const f16x8*>(&lds[boff + 4096]);
#pragma unroll
                for (int mf = 0; mf < 4; ++mf) {
                    f32x4 c = accg[g][mf][nf];
                    c = __builtin_amdgcn_mfma_f32_16x16x32_f16(af[0][mf], bh, c, 0, 0, 0);
                    c = __builtin_amdgcn_mfma_f32_16x16x32_f16(af[0][mf], bl, c, 0, 0, 0);
                    c = __builtin_amdgcn_mfma_f32_16x16x32_f16(af[1][mf], bh, c, 0, 0, 0);
                    accg[g][mf][nf] = c;
                }
            }
        }
        __syncthreads();
    }

#pragma unroll
    for (int nf = 0; nf < 4; ++nf) {
        int gc = colBase + wc * 64 + nf * 16 + frow;
        float br = bih[gc] + bhh[gc];
        float bz = bih[256 + gc] + bhh[256 + gc];
#pragma unroll
        for (int mf = 0; mf < 4; ++mf) {
#pragma unroll
            for (int j = 0; j < 4; ++j) {
                int gr = rowBase + wr * 64 + mf * 16 + kg * 4 + j;
                if (gr < M) {
                    size_t off = (size_t)gr * DD + gc;
                    RZ[off]        = f2h(sigmoidf_(accg[0][mf][nf][j] + br));
                    RZ[psRZ + off] = f2h(sigmoidf_(accg[1][mf][nf][j] + bz));
                }
            }
        }
    }
}

// ---------------- fused n-gate + GRU update GEMM ----------------
// xn = msg @ Wih_n^T (k<256 half), hn = x @ Whh_n^T (k>=256 half);
// T = tanh(xn + bih_n + r*(hn + bhh_n)); out = (1-z)*T + z*x.
// pA2 (x planes) doubles as the blend source in the epilogue.
template <bool FINAL>
__global__ __launch_bounds__(256, 2)
void gemm_n(const u16* __restrict__ pA1, const u16* __restrict__ pA2, size_t psA,
            const u16* __restrict__ pB1, const u16* __restrict__ pB2, size_t psB,
            const float* __restrict__ bihn, const float* __restrict__ bhhn,
            const u16* __restrict__ RZ, size_t psRZ,
            float* __restrict__ outF, u16* __restrict__ outP, size_t psO, int M) {
    __shared__ u16 lds[16384];   // A: hi 0, lo 4096; B: hi 8192, lo 12288

    const int tid = threadIdx.x;
    const int lane = tid & 63;
    const int wv = tid >> 6;
    const int wr = wv >> 1;
    const int wc = wv & 1;
    const int frow = lane & 15;
    const int kg = lane >> 4;
    const int rowBase = blockIdx.x * BM;
    const int colBase = blockIdx.y * BN;

    int offj[8]; int ldsj[8]; bool isBj[8];
#pragma unroll
    for (int j = 0; j < 8; ++j) {
        int q = wv * 8 + j;
        bool isB = q >= 16;
        int p = (q >> 3) & 1;
        int sub = q & 7;
        int row = sub * 16 + (lane >> 2);
        int chunk = (lane & 3) ^ ((row >> 1) & 3);
        int ps = isB ? (int)psB : (int)psA;
        int grow = (isB ? colBase : rowBase) + row;
        offj[j] = p * ps + grow * DD + chunk * 8;
        ldsj[j] = q * 512;
        isBj[j] = isB;
    }

    f32x4 accx[4][4] = {};
    f32x4 acch[4][4] = {};

    auto half = [&](const u16* Ab, const u16* Bb, f32x4 (&acc)[4][4]) {
        for (int kc = 0; kc < DD; kc += BK) {
#pragma unroll
            for (int j = 0; j < 8; ++j)
                gload16((isBj[j] ? Bb : Ab) + offj[j] + kc, &lds[ldsj[j]]);
            __syncthreads();

            f16x8 af[2][4];
#pragma unroll
            for (int mf = 0; mf < 4; ++mf) {
                int row = wr * 64 + mf * 16 + frow;
                int off = row * 32 + ((kg ^ ((row >> 1) & 3)) * 8);
                af[0][mf] = *reinterpret_cast<const f16x8*>(&lds[off]);
                af[1][mf] = *reinterpret_cast<const f16x8*>(&lds[4096 + off]);
            }
#pragma unroll
            for (int nf = 0; nf < 4; ++nf) {
                int brow = wc * 64 + nf * 16 + frow;
                int boff = 8192 + brow * 32 + ((kg ^ ((brow >> 1) & 3)) * 8);
                f16x8 bh = *reinterpret_cast<const f16x8*>(&lds[boff]);
                f16x8 bl = *reinterpret_cast<const f16x8*>(&lds[boff + 4096]);
#pragma unroll
                for (int mf = 0; mf < 4; ++mf) {
                    f32x4 c = acc[mf][nf];
                    c = __builtin_amdgcn_mfma_f32_16x16x32_f16(af[0][mf], bh, c, 0, 0, 0);
                    c = __builtin_amdgcn_mfma_f32_16x16x32_f16(af[0][mf], bl, c, 0, 0, 0);
                    c = __builtin_amdgcn_mfma_f32_16x16x32_f16(af[1][mf], bh, c, 0, 0, 0);
                    acc[mf][nf] = c;
                }
            }
            __syncthreads();
        }
    };
    half(pA1, pB1, accx);   // xn = msg @ Wih_n^T
    half(pA2, pB2, acch);   // hn = x   @ Whh_n^T

#pragma unroll
    for (int nf = 0; nf < 4; ++nf) {
        int gc = colBase + wc * 64 + nf * 16 + frow;
        float bx = bihn[gc];
        float bh = bhhn[gc];
#pragma unroll
        for (int mf = 0; mf < 4; ++mf) {
#pragma unroll
            for (int j = 0; j < 4; ++j) {
                int gr = rowBase + wr * 64 + mf * 16 + kg * 4 + j;
                if (gr < M) {
                    size_t off = (size_t)gr * DD + gc;
                    float r = h2f(RZ[off]);
                    float z = h2f(RZ[psRZ + off]);
                    float T = tanhf(accx[mf][nf][j] + bx + r * (acch[mf][nf][j] + bh));
                    float x = h2f(pA2[off]) + h2f(pA2[psA + off]);
                    float o = (1.0f - z) * T + z * x;
                    if (FINAL) outF[off] = o;
                    else       store_planes(outP, psO, off, o);
                }
            }
        }
    }
}

// ---------------- segment sum (gather over CSR) -> msg planes ----------------
__global__ __launch_bounds__(256)
void segsum_kernel(const float* __restrict__ h, const int* __restrict__ row_ptr,
                   const int* __restrict__ csr_src, u16* __restrict__ msgP,
                   size_t ps, int n) {
    int node = blockIdx.x * 4 + threadIdx.y;
    if (node >= n) return;
    int d4 = threadIdx.x * 4;
    int s = row_ptr[node];
    int e = row_ptr[node + 1];
    float4 acc = make_float4(0.f, 0.f, 0.f, 0.f);
    for (int j = s; j < e; ++j) {
        int sn = csr_src[j];
        float4 v = *reinterpret_cast<const float4*>(&h[(size_t)sn * DD + d4]);
        acc.x += v.x; acc.y += v.y; acc.z += v.z; acc.w += v.w;
    }
    size_t off = (size_t)node * DD + d4;
    u16 h0,l0,h1,l1,h2,l2,h3,l3;
    split2(acc.x, h0,l0); split2(acc.y, h1,l1);
    split2(acc.z, h2,l2); split2(acc.w, h3,l3);
    *reinterpret_cast<uint2*>(&msgP[off])      = make_uint2(pk(h0,h1), pk(h2,h3));
    *reinterpret_cast<uint2*>(&msgP[ps + off]) = make_uint2(pk(l0,l1), pk(l2,l3));
}

// ---------------- launch ----------------

extern "C" void kernel_launch(void* const* d_in, const int* in_sizes, int n_in,
                              void* d_out, int out_size, void* d_ws, size_t ws_size,
                              hipStream_t stream) {
    const float* x0  = (const float*)d_in[0];
    const float* W1  = (const float*)d_in[1];
    const float* b1  = (const float*)d_in[2];
    const float* W2  = (const float*)d_in[3];
    const float* b2  = (const float*)d_in[4];
    const float* Wih = (const float*)d_in[5];
    const float* bih = (const float*)d_in[6];
    const float* Whh = (const float*)d_in[7];
    const float* bhh = (const float*)d_in[8];
    const int*   src = (const int*)d_in[9];
    const int*   dst = (const int*)d_in[10];

    // workspace layout (~211.3 MB — proven footprint)
    char* ws = (char*)d_ws;
    const size_t PSA = (size_t)NNP * DD;              // elems per activation plane
    const size_t SP  = PSA * 2 * sizeof(u16);         // 51.25 MB (2 fp16 planes)
    const size_t NB  = PSA * sizeof(float);           // 51.25 MB
    const size_t PSW2 = (size_t)DD * DD;              // 65536
    const size_t PSW3 = (size_t)3 * DD * DD;          // 196608
    u16* XP0   = (u16*)(ws);                          // x planes (even steps)
    u16* XP1   = (u16*)(ws + SP);                     // x planes (odd steps)
    u16* TP    = (u16*)(ws + 2 * SP);                 // t1 planes, then msg planes
    float* F1  = (float*)(ws + 3 * SP);               // h fp32; then RZ fp16 (aliased)
    u16* W1P   = (u16*)(ws + 3 * SP + NB);
    u16* W2P   = W1P + 2 * PSW2;
    u16* WIHP  = W2P + 2 * PSW2;
    u16* WHHP  = WIHP + 2 * PSW3;
    int* counts  = (int*)(WHHP + 2 * PSW3);
    int* cursor  = counts + NN;
    int* row_ptr = cursor + NN;                       // NN+1 ints
    int* csr     = row_ptr + NN + 8;                  // NE ints
    const size_t needed = 3 * SP + NB + (4 * PSW2 + 4 * PSW3) * sizeof(u16)
                        + (size_t)(2 * NN + NN + 9 + NE) * sizeof(int);
    if (ws_size < needed) return;   // clean fail instead of OOB crash

    u16* RZ = (u16*)F1;             // r plane at 0, z plane at +PSA (h is dead by then)
    float* FOUT = (float*)d_out;

    // CSR build
    zero_kernel<<<(2 * NN + 255) / 256, 256, 0, stream>>>(counts, 2 * NN);
    hist_kernel<<<(NE + 255) / 256, 256, 0, stream>>>(dst, counts, NE);
    scan_kernel<<<1, 1024, 0, stream>>>(counts, row_ptr, NN);
    fill_kernel<<<(NE + 255) / 256, 256, 0, stream>>>(src, dst, row_ptr, cursor, csr, NE);

    // pre-split weights (once) and x0 -> XP0
    split_rows<<<DD, 256, 0, stream>>>(W1, W1P, PSW2, DD);
    split_rows<<<DD, 256, 0, stream>>>(W2, W2P, PSW2, DD);
    split_rows<<<3 * DD, 256, 0, stream>>>(Wih, WIHP, PSW3, 3 * DD);
    split_rows<<<3 * DD, 256, 0, stream>>>(Whh, WHHP, PSW3, 3 * DD);
    split_rows<<<NNP, 256, 0, stream>>>(x0, XP0, PSA, NN);

    const dim3 grid(NNP / BM, DD / BN);   // 391 x 2

    for (int s = 0; s < NSTEPS; ++s) {
        u16* XPc = (s & 1) ? XP1 : XP0;
        u16* XPn = (s & 1) ? XP0 : XP1;

        // t1 = ReLU(x @ W1^T + b1) -> TP planes
        gemm_planes<MODE_RELU_P><<<grid, 256, 0, stream>>>(
            XPc, PSA, W1P, PSW2, b1, nullptr, TP, PSA, NN);
        // h = t1 @ W2^T + b2 -> F1 fp32
        gemm_planes<MODE_PLAIN_F><<<grid, 256, 0, stream>>>(
            TP, PSA, W2P, PSW2, b2, F1, nullptr, 0, NN);
        // msg = segment_sum(h[src], dst) -> TP planes (t1 dead)
        segsum_kernel<<<dim3((NN + 3) / 4), dim3(64, 4), 0, stream>>>(
            F1, row_ptr, csr, TP, PSA, NN);
        // r,z = sig([msg|x] @ [W_r|W_z]^T + biases) -> RZ fp16 (h dead)
        gemm_rz<<<grid, 256, 0, stream>>>(
            TP, XPc, PSA, WIHP, WHHP, PSW3, bih, bhh, RZ, PSA, NN);
        // xn,hn + T + blend -> x_next planes (or fp32 d_out at final step)
        if (s < NSTEPS - 1) {
            gemm_n<false><<<grid, 256, 0, stream>>>(
                TP, XPc, PSA, WIHP + 512 * DD, WHHP + 512 * DD, PSW3,
                bih + 512, bhh + 512, RZ, PSA, nullptr, XPn, PSA, NN);
        } else {
            gemm_n<true><<<grid, 256, 0, stream>>>(
                TP, XPc, PSA, WIHP + 512 * DD, WHHP + 512 * DD, PSW3,
                bih + 512, bhh + 512, RZ, PSA, FOUT, nullptr, 0, NN);
        }
    }
}

// Round 10
// 2800.331 us; speedup vs baseline: 1.2515x; 1.0383x over previous
//
#include <hip/hip_runtime.h>
#include <hip/hip_bf16.h>
#include <math.h>

// Problem constants
#define NN 50000
#define NNP 50048       // rows padded to multiple of BM=128
#define NE 800000
#define DD 256
#define NSTEPS 6

// GEMM tiling (R6-proven champion geometry)
#define BM 128
#define BN 128
#define BK 32

typedef unsigned short u16;
typedef _Float16 f16x8 __attribute__((ext_vector_type(8)));
typedef _Float16 f16x4 __attribute__((ext_vector_type(4)));
typedef float f32x4 __attribute__((ext_vector_type(4)));

#define MODE_RELU_P  0   // relu(v+b1) -> 2 planes
#define MODE_PLAIN_H 1   // v+b1 -> single fp16 plane

__device__ __forceinline__ float sigmoidf_(float v) {
    return 1.0f / (1.0f + expf(-v));
}
__device__ __forceinline__ u16 f2h(float v) {
    _Float16 h = (_Float16)v;            // RNE
    u16 u; __builtin_memcpy(&u, &h, 2); return u;
}
__device__ __forceinline__ float h2f(u16 u) {
    _Float16 h; __builtin_memcpy(&h, &u, 2); return (float)h;
}
// fp16 2-way split: v ~= h + l to 2^-22 relative
__device__ __forceinline__ void split2(float v, u16& h, u16& l) {
    h = f2h(v);
    float r = v - h2f(h);
    l = f2h(r);
}
__device__ __forceinline__ unsigned pk(u16 a, u16 b) {
    return (unsigned)a | ((unsigned)b << 16);
}
__device__ __forceinline__ void store_planes(u16* base, size_t ps, size_t off, float v) {
    u16 h, l; split2(v, h, l);
    base[off] = h; base[ps + off] = l;
}
__device__ __forceinline__ void gload16(const void* g, void* l) {
    __builtin_amdgcn_global_load_lds(
        (const __attribute__((address_space(1))) void*)g,
        (__attribute__((address_space(3))) void*)l, 16, 0, 0);
}

// ---------------- CSR build (verified R1-R9) ----------------

__global__ void zero_kernel(int* __restrict__ p, int n) {
    int i = blockIdx.x * blockDim.x + threadIdx.x;
    if (i < n) p[i] = 0;
}
__global__ void hist_kernel(const int* __restrict__ dst, int* __restrict__ counts, int E) {
    int e = blockIdx.x * blockDim.x + threadIdx.x;
    if (e < E) atomicAdd(&counts[dst[e]], 1);
}
__global__ void scan_kernel(const int* __restrict__ counts, int* __restrict__ row_ptr, int n) {
    __shared__ int buf[1024];
    __shared__ int carry;
    const int tid = threadIdx.x;
    if (tid == 0) carry = 0;
    __syncthreads();
    for (int base = 0; base < n; base += 1024) {
        int i = base + tid;
        int v = (i < n) ? counts[i] : 0;
        buf[tid] = v;
        __syncthreads();
        for (int off = 1; off < 1024; off <<= 1) {
            int t = (tid >= off) ? buf[tid - off] : 0;
            __syncthreads();
            buf[tid] += t;
            __syncthreads();
        }
        if (i < n) row_ptr[i] = carry + buf[tid] - v;
        __syncthreads();
        if (tid == 0) carry += buf[1023];
        __syncthreads();
    }
    if (threadIdx.x == 0) row_ptr[n] = carry;
}
__global__ void fill_kernel(const int* __restrict__ src, const int* __restrict__ dst,
                            const int* __restrict__ row_ptr, int* __restrict__ cursor,
                            int* __restrict__ csr_src, int E) {
    int e = blockIdx.x * blockDim.x + threadIdx.x;
    if (e < E) {
        int d = dst[e];
        int p = atomicAdd(&cursor[d], 1);
        csr_src[row_ptr[d] + p] = src[e];
    }
}

// ---------------- fp32 -> 2 fp16 planes (rows padded w/ zero) ----------------
__global__ void split_rows(const float* __restrict__ src, u16* __restrict__ dst,
                           size_t pstride, int srcRows) {
    int row = blockIdx.x;
    int col = threadIdx.x;
    size_t off = (size_t)row * DD + col;
    float v = (row < srcRows) ? src[off] : 0.0f;
    store_planes(dst, pstride, off, v);
}

// ---------------- split-plane fp16 MFMA GEMM (R6 champion, K=256) ----------------
// C = epilogue(A @ W^T + bias). A,B as 2 fp16 planes (hi/lo), plane-major.
// 3-term product (hh, hl, lh) == fp32-grade (2^-22) precision.
template <int MODE>
__global__ __launch_bounds__(256, 4)
void gemm_planes(const u16* __restrict__ pA, size_t psA,
                 const u16* __restrict__ pB, size_t psB,
                 const float* __restrict__ bias1,
                 u16* __restrict__ outP, size_t psO, int M) {
    __shared__ u16 lds[16384];   // A: 2 planes x [128][32] = 8192; B same at +8192

    const int tid = threadIdx.x;
    const int lane = tid & 63;
    const int wv = tid >> 6;
    const int wr = wv >> 1;            // wave row 0..1 (64 rows)
    const int wc = wv & 1;             // wave col 0..1 (64 cols)
    const int frow = lane & 15;
    const int kg = lane >> 4;
    const int rowBase = blockIdx.x * BM;
    const int colBase = blockIdx.y * BN;

    // staging plan: 32 x 1KB wave-issues per tile, 8 per wave (0 bank conflicts).
    int offj[8]; int ldsj[8]; bool isBj[8];
#pragma unroll
    for (int j = 0; j < 8; ++j) {
        int q = wv * 8 + j;
        bool isB = q >= 16;
        int p = (q >> 3) & 1;
        int sub = q & 7;
        int row = sub * 16 + (lane >> 2);
        int chunk = (lane & 3) ^ ((row >> 1) & 3);
        int ps = isB ? (int)psB : (int)psA;
        int grow = (isB ? colBase : rowBase) + row;
        offj[j] = p * ps + grow * DD + chunk * 8;
        ldsj[j] = q * 512;
        isBj[j] = isB;
    }

    f32x4 acc[4][4] = {};

    for (int kc = 0; kc < DD; kc += BK) {
#pragma unroll
        for (int j = 0; j < 8; ++j)
            gload16((isBj[j] ? pB : pA) + offj[j] + kc, &lds[ldsj[j]]);
        __syncthreads();

        f16x8 af[2][4];
#pragma unroll
        for (int mf = 0; mf < 4; ++mf) {
            int row = wr * 64 + mf * 16 + frow;
            int off = row * 32 + ((kg ^ ((row >> 1) & 3)) * 8);
            af[0][mf] = *reinterpret_cast<const f16x8*>(&lds[off]);
            af[1][mf] = *reinterpret_cast<const f16x8*>(&lds[4096 + off]);
        }
#pragma unroll
        for (int nf = 0; nf < 4; ++nf) {
            int brow = wc * 64 + nf * 16 + frow;
            int boff = 8192 + brow * 32 + ((kg ^ ((brow >> 1) & 3)) * 8);
            f16x8 bh = *reinterpret_cast<const f16x8*>(&lds[boff]);
            f16x8 bl = *reinterpret_cast<const f16x8*>(&lds[boff + 4096]);
#pragma unroll
            for (int mf = 0; mf < 4; ++mf) {
                f32x4 c = acc[mf][nf];
                c = __builtin_amdgcn_mfma_f32_16x16x32_f16(af[0][mf], bh, c, 0, 0, 0);
                c = __builtin_amdgcn_mfma_f32_16x16x32_f16(af[0][mf], bl, c, 0, 0, 0);
                c = __builtin_amdgcn_mfma_f32_16x16x32_f16(af[1][mf], bh, c, 0, 0, 0);
                acc[mf][nf] = c;
            }
        }
        __syncthreads();
    }

#pragma unroll
    for (int nf = 0; nf < 4; ++nf) {
        int gc = colBase + wc * 64 + nf * 16 + frow;
        float b1v = bias1[gc];
#pragma unroll
        for (int mf = 0; mf < 4; ++mf) {
            f32x4 a = acc[mf][nf];
#pragma unroll
            for (int j = 0; j < 4; ++j) {
                int gr = rowBase + wr * 64 + mf * 16 + kg * 4 + j;
                if (gr < M) {
                    float v = a[j] + b1v;
                    size_t off = (size_t)gr * DD + gc;
                    if (MODE == MODE_RELU_P) store_planes(outP, psO, off, fmaxf(v, 0.0f));
                    else                     outP[off] = f2h(v);   // h: single fp16 plane
                }
            }
        }
    }
}

// ---------------- fused r,z gate GEMM (K=512, 2 gates per A-stage) ----------------
// r = sig([msg|x] @ [Wih_r|Whh_r]^T + bih_r + bhh_r); z likewise with _z rows.
// A staged once per k-iter serves BOTH gate panels: 96 MFMA / 48KB staged.
// Outputs r,z as fp16 into RZ (plane 0 = r, plane 1 = z).
__global__ __launch_bounds__(256, 2)
void gemm_rz(const u16* __restrict__ pA1, const u16* __restrict__ pA2, size_t psA,
             const u16* __restrict__ pB1, const u16* __restrict__ pB2, size_t psB,
             const float* __restrict__ bih, const float* __restrict__ bhh,
             u16* __restrict__ RZ, size_t psRZ, int M) {
    // A: hi 0, lo 4096 | B gate0(r): hi 8192, lo 12288 | gate1(z): hi 16384, lo 20480
    __shared__ u16 lds[24576];   // 48 KB

    const int tid = threadIdx.x;
    const int lane = tid & 63;
    const int wv = tid >> 6;
    const int wr = wv >> 1;
    const int wc = wv & 1;
    const int frow = lane & 15;
    const int kg = lane >> 4;
    const int rowBase = blockIdx.x * BM;
    const int colBase = blockIdx.y * BN;

    // staging: 48 x 1KB wave-issues per tile, 12 per wave.
    int offj[12]; int ldsj[12]; bool isBj[12];
#pragma unroll
    for (int j = 0; j < 12; ++j) {
        int q = wv * 12 + j;
        bool isB = q >= 16;
        int row, ldso, eoff;
        if (!isB) {
            int p = (q >> 3) & 1; int sub = q & 7;
            row = sub * 16 + (lane >> 2);
            int chunk = (lane & 3) ^ ((row >> 1) & 3);
            eoff = p * (int)psA + (rowBase + row) * DD + chunk * 8;
            ldso = q * 512;
        } else {
            int qb = q - 16;                  // 0..31
            int gate = qb >> 4;               // 0=r, 1=z
            int p = (qb >> 3) & 1; int sub = qb & 7;
            row = sub * 16 + (lane >> 2);
            int chunk = (lane & 3) ^ ((row >> 1) & 3);
            eoff = p * (int)psB + (gate * 256 + colBase + row) * DD + chunk * 8;
            ldso = 8192 + qb * 512;
        }
        offj[j] = eoff; ldsj[j] = ldso; isBj[j] = isB;
    }

    f32x4 accg[2][4][4] = {};

    for (int k0 = 0; k0 < 512; k0 += BK) {
        const u16* Ab; const u16* Bb; int kc;
        if (k0 < DD) { Ab = pA1; Bb = pB1; kc = k0; }
        else         { Ab = pA2; Bb = pB2; kc = k0 - DD; }

#pragma unroll
        for (int j = 0; j < 12; ++j)
            gload16((isBj[j] ? Bb : Ab) + offj[j] + kc, &lds[ldsj[j]]);
        __syncthreads();

        f16x8 af[2][4];
#pragma unroll
        for (int mf = 0; mf < 4; ++mf) {
            int row = wr * 64 + mf * 16 + frow;
            int off = row * 32 + ((kg ^ ((row >> 1) & 3)) * 8);
            af[0][mf] = *reinterpret_cast<const f16x8*>(&lds[off]);
            af[1][mf] = *reinterpret_cast<const f16x8*>(&lds[4096 + off]);
        }
#pragma unroll
        for (int g = 0; g < 2; ++g) {
#pragma unroll
            for (int nf = 0; nf < 4; ++nf) {
                int brow = wc * 64 + nf * 16 + frow;
                int boff = 8192 + g * 8192 + brow * 32 + ((kg ^ ((brow >> 1) & 3)) * 8);
                f16x8 bh = *reinterpret_cast<const f16x8*>(&lds[boff]);
                f16x8 bl = *reinterpret_cast<const f16x8*>(&lds[boff + 4096]);
#pragma unroll
                for (int mf = 0; mf < 4; ++mf) {
                    f32x4 c = accg[g][mf][nf];
                    c = __builtin_amdgcn_mfma_f32_16x16x32_f16(af[0][mf], bh, c, 0, 0, 0);
                    c = __builtin_amdgcn_mfma_f32_16x16x32_f16(af[0][mf], bl, c, 0, 0, 0);
                    c = __builtin_amdgcn_mfma_f32_16x16x32_f16(af[1][mf], bh, c, 0, 0, 0);
                    accg[g][mf][nf] = c;
                }
            }
        }
        __syncthreads();
    }

#pragma unroll
    for (int nf = 0; nf < 4; ++nf) {
        int gc = colBase + wc * 64 + nf * 16 + frow;
        float br = bih[gc] + bhh[gc];
        float bz = bih[256 + gc] + bhh[256 + gc];
#pragma unroll
        for (int mf = 0; mf < 4; ++mf) {
#pragma unroll
            for (int j = 0; j < 4; ++j) {
                int gr = rowBase + wr * 64 + mf * 16 + kg * 4 + j;
                if (gr < M) {
                    size_t off = (size_t)gr * DD + gc;
                    RZ[off]        = f2h(sigmoidf_(accg[0][mf][nf][j] + br));
                    RZ[psRZ + off] = f2h(sigmoidf_(accg[1][mf][nf][j] + bz));
                }
            }
        }
    }
}

// ---------------- fused n-gate + GRU update GEMM ----------------
// xn = msg @ Wih_n^T, hn = x @ Whh_n^T (two K=256 half-loops);
// T = tanh(xn + bih_n + r*(hn + bhh_n)); out = (1-z)*T + z*x.
template <bool FINAL>
__global__ __launch_bounds__(256, 3)
void gemm_n(const u16* __restrict__ pA1, const u16* __restrict__ pA2, size_t psA,
            const u16* __restrict__ pB1, const u16* __restrict__ pB2, size_t psB,
            const float* __restrict__ bihn, const float* __restrict__ bhhn,
            const u16* __restrict__ RZ, size_t psRZ,
            float* __restrict__ outF, u16* __restrict__ outP, size_t psO, int M) {
    __shared__ u16 lds[16384];   // A: hi 0, lo 4096; B: hi 8192, lo 12288

    const int tid = threadIdx.x;
    const int lane = tid & 63;
    const int wv = tid >> 6;
    const int wr = wv >> 1;
    const int wc = wv & 1;
    const int frow = lane & 15;
    const int kg = lane >> 4;
    const int rowBase = blockIdx.x * BM;
    const int colBase = blockIdx.y * BN;

    int offj[8]; int ldsj[8]; bool isBj[8];
#pragma unroll
    for (int j = 0; j < 8; ++j) {
        int q = wv * 8 + j;
        bool isB = q >= 16;
        int p = (q >> 3) & 1;
        int sub = q & 7;
        int row = sub * 16 + (lane >> 2);
        int chunk = (lane & 3) ^ ((row >> 1) & 3);
        int ps = isB ? (int)psB : (int)psA;
        int grow = (isB ? colBase : rowBase) + row;
        offj[j] = p * ps + grow * DD + chunk * 8;
        ldsj[j] = q * 512;
        isBj[j] = isB;
    }

    f32x4 accx[4][4] = {};
    f32x4 acch[4][4] = {};

    auto half = [&](const u16* Ab, const u16* Bb, f32x4 (&acc)[4][4]) {
        for (int kc = 0; kc < DD; kc += BK) {
#pragma unroll
            for (int j = 0; j < 8; ++j)
                gload16((isBj[j] ? Bb : Ab) + offj[j] + kc, &lds[ldsj[j]]);
            __syncthreads();

            f16x8 af[2][4];
#pragma unroll
            for (int mf = 0; mf < 4; ++mf) {
                int row = wr * 64 + mf * 16 + frow;
                int off = row * 32 + ((kg ^ ((row >> 1) & 3)) * 8);
                af[0][mf] = *reinterpret_cast<const f16x8*>(&lds[off]);
                af[1][mf] = *reinterpret_cast<const f16x8*>(&lds[4096 + off]);
            }
#pragma unroll
            for (int nf = 0; nf < 4; ++nf) {
                int brow = wc * 64 + nf * 16 + frow;
                int boff = 8192 + brow * 32 + ((kg ^ ((brow >> 1) & 3)) * 8);
                f16x8 bh = *reinterpret_cast<const f16x8*>(&lds[boff]);
                f16x8 bl = *reinterpret_cast<const f16x8*>(&lds[boff + 4096]);
#pragma unroll
                for (int mf = 0; mf < 4; ++mf) {
                    f32x4 c = acc[mf][nf];
                    c = __builtin_amdgcn_mfma_f32_16x16x32_f16(af[0][mf], bh, c, 0, 0, 0);
                    c = __builtin_amdgcn_mfma_f32_16x16x32_f16(af[0][mf], bl, c, 0, 0, 0);
                    c = __builtin_amdgcn_mfma_f32_16x16x32_f16(af[1][mf], bh, c, 0, 0, 0);
                    acc[mf][nf] = c;
                }
            }
            __syncthreads();
        }
    };
    half(pA1, pB1, accx);   // xn = msg @ Wih_n^T
    half(pA2, pB2, acch);   // hn = x   @ Whh_n^T

#pragma unroll
    for (int nf = 0; nf < 4; ++nf) {
        int gc = colBase + wc * 64 + nf * 16 + frow;
        float bx = bihn[gc];
        float bh = bhhn[gc];
#pragma unroll
        for (int mf = 0; mf < 4; ++mf) {
#pragma unroll
            for (int j = 0; j < 4; ++j) {
                int gr = rowBase + wr * 64 + mf * 16 + kg * 4 + j;
                if (gr < M) {
                    size_t off = (size_t)gr * DD + gc;
                    float r = h2f(RZ[off]);
                    float z = h2f(RZ[psRZ + off]);
                    float T = tanhf(accx[mf][nf][j] + bx + r * (acch[mf][nf][j] + bh));
                    float x = h2f(pA2[off]) + h2f(pA2[psA + off]);
                    float o = (1.0f - z) * T + z * x;
                    if (FINAL) outF[off] = o;
                    else       store_planes(outP, psO, off, o);
                }
            }
        }
    }
}

// ---------------- segment sum (gather over fp16 h table) -> msg planes ----------------
__global__ __launch_bounds__(256)
void segsum_kernel(const u16* __restrict__ hp, const int* __restrict__ row_ptr,
                   const int* __restrict__ csr_src, u16* __restrict__ msgP,
                   size_t ps, int n) {
    int node = blockIdx.x * 4 + threadIdx.y;
    if (node >= n) return;
    int d4 = threadIdx.x * 4;
    int s = row_ptr[node];
    int e = row_ptr[node + 1];
    float4 acc = make_float4(0.f, 0.f, 0.f, 0.f);
    for (int j = s; j < e; ++j) {
        int sn = csr_src[j];
        f16x4 v = *reinterpret_cast<const f16x4*>(&hp[(size_t)sn * DD + d4]);
        acc.x += (float)v[0]; acc.y += (float)v[1];
        acc.z += (float)v[2]; acc.w += (float)v[3];
    }
    size_t off = (size_t)node * DD + d4;
    u16 h0,l0,h1,l1,h2,l2,h3,l3;
    split2(acc.x, h0,l0); split2(acc.y, h1,l1);
    split2(acc.z, h2,l2); split2(acc.w, h3,l3);
    *reinterpret_cast<uint2*>(&msgP[off])      = make_uint2(pk(h0,h1), pk(h2,h3));
    *reinterpret_cast<uint2*>(&msgP[ps + off]) = make_uint2(pk(l0,l1), pk(l2,l3));
}

// ---------------- launch ----------------

extern "C" void kernel_launch(void* const* d_in, const int* in_sizes, int n_in,
                              void* d_out, int out_size, void* d_ws, size_t ws_size,
                              hipStream_t stream) {
    const float* x0  = (const float*)d_in[0];
    const float* W1  = (const float*)d_in[1];
    const float* b1  = (const float*)d_in[2];
    const float* W2  = (const float*)d_in[3];
    const float* b2  = (const float*)d_in[4];
    const float* Wih = (const float*)d_in[5];
    const float* bih = (const float*)d_in[6];
    const float* Whh = (const float*)d_in[7];
    const float* bhh = (const float*)d_in[8];
    const int*   src = (const int*)d_in[9];
    const int*   dst = (const int*)d_in[10];

    // workspace layout (~211.3 MB — proven footprint)
    char* ws = (char*)d_ws;
    const size_t PSA = (size_t)NNP * DD;              // elems per activation plane
    const size_t SP  = PSA * 2 * sizeof(u16);         // 51.25 MB (2 fp16 planes)
    const size_t NB  = PSA * sizeof(float);           // 51.25 MB
    const size_t PSW2 = (size_t)DD * DD;              // 65536
    const size_t PSW3 = (size_t)3 * DD * DD;          // 196608
    u16* XP0   = (u16*)(ws);                          // x planes (even steps)
    u16* XP1   = (u16*)(ws + SP);                     // x planes (odd steps)
    u16* TP    = (u16*)(ws + 2 * SP);                 // t1 planes, then msg planes
    u16* HP    = (u16*)(ws + 3 * SP);                 // h fp16 plane; then RZ (aliased)
    u16* W1P   = (u16*)(ws + 3 * SP + NB);
    u16* W2P   = W1P + 2 * PSW2;
    u16* WIHP  = W2P + 2 * PSW2;
    u16* WHHP  = WIHP + 2 * PSW3;
    int* counts  = (int*)(WHHP + 2 * PSW3);
    int* cursor  = counts + NN;
    int* row_ptr = cursor + NN;                       // NN+1 ints
    int* csr     = row_ptr + NN + 8;                  // NE ints
    const size_t needed = 3 * SP + NB + (4 * PSW2 + 4 * PSW3) * sizeof(u16)
                        + (size_t)(2 * NN + NN + 9 + NE) * sizeof(int);
    if (ws_size < needed) return;   // clean fail instead of OOB crash

    u16* RZ = HP;                   // r plane at 0, z plane at +PSA (h dead by then)
    float* FOUT = (float*)d_out;

    // CSR build
    zero_kernel<<<(2 * NN + 255) / 256, 256, 0, stream>>>(counts, 2 * NN);
    hist_kernel<<<(NE + 255) / 256, 256, 0, stream>>>(dst, counts, NE);
    scan_kernel<<<1, 1024, 0, stream>>>(counts, row_ptr, NN);
    fill_kernel<<<(NE + 255) / 256, 256, 0, stream>>>(src, dst, row_ptr, cursor, csr, NE);

    // pre-split weights (once) and x0 -> XP0
    split_rows<<<DD, 256, 0, stream>>>(W1, W1P, PSW2, DD);
    split_rows<<<DD, 256, 0, stream>>>(W2, W2P, PSW2, DD);
    split_rows<<<3 * DD, 256, 0, stream>>>(Wih, WIHP, PSW3, 3 * DD);
    split_rows<<<3 * DD, 256, 0, stream>>>(Whh, WHHP, PSW3, 3 * DD);
    split_rows<<<NNP, 256, 0, stream>>>(x0, XP0, PSA, NN);

    const dim3 grid(NNP / BM, DD / BN);   // 391 x 2

    for (int s = 0; s < NSTEPS; ++s) {
        u16* XPc = (s & 1) ? XP1 : XP0;
        u16* XPn = (s & 1) ? XP0 : XP1;

        // t1 = ReLU(x @ W1^T + b1) -> TP planes
        gemm_planes<MODE_RELU_P><<<grid, 256, 0, stream>>>(
            XPc, PSA, W1P, PSW2, b1, TP, PSA, NN);
        // h = t1 @ W2^T + b2 -> HP (single fp16 plane)
        gemm_planes<MODE_PLAIN_H><<<grid, 256, 0, stream>>>(
            TP, PSA, W2P, PSW2, b2, HP, 0, NN);
        // msg = segment_sum(h[src], dst) -> TP planes (t1 dead)
        segsum_kernel<<<dim3((NN + 3) / 4), dim3(64, 4), 0, stream>>>(
            HP, row_ptr, csr, TP, PSA, NN);
        // r,z = sig([msg|x] @ [W_r|W_z]^T + biases) -> RZ fp16 (h dead)
        gemm_rz<<<grid, 256, 0, stream>>>(
            TP, XPc, PSA, WIHP, WHHP, PSW3, bih, bhh, RZ, PSA, NN);
        // xn,hn + T + blend -> x_next planes (or fp32 d_out at final step)
        if (s < NSTEPS - 1) {
            gemm_n<false><<<grid, 256, 0, stream>>>(
                TP, XPc, PSA, WIHP + 512 * DD, WHHP + 512 * DD, PSW3,
                bih + 512, bhh + 512, RZ, PSA, nullptr, XPn, PSA, NN);
        } else {
            gemm_n<true><<<grid, 256, 0, stream>>>(
                TP, XPc, PSA, WIHP + 512 * DD, WHHP + 512 * DD, PSW3,
                bih + 512, bhh + 512, RZ, PSA, FOUT, nullptr, 0, NN);
        }
    }
}

// Round 11
// 2462.533 us; speedup vs baseline: 1.4232x; 1.1372x over previous
//
#include <hip/hip_runtime.h>
#include <hip/hip_bf16.h>
#include <math.h>

// Problem constants
#define NN 50000
#define NNP 50048       // rows padded to multiple of BM=128
#define NE 800000
#define DD 256
#define NSTEPS 6

// GEMM tiling (R6-proven champion geometry)
#define BM 128
#define BN 128
#define BK 32

typedef unsigned short u16;
typedef _Float16 f16x8 __attribute__((ext_vector_type(8)));
typedef _Float16 f16x4 __attribute__((ext_vector_type(4)));
typedef float f32x4 __attribute__((ext_vector_type(4)));

#define MODE_RELU_P  0   // relu(v+b1) -> 2 planes
#define MODE_PLAIN_H 1   // v+b1 -> single fp16 plane

__device__ __forceinline__ float sigmoidf_(float v) {
    return 1.0f / (1.0f + expf(-v));
}
__device__ __forceinline__ u16 f2h(float v) {
    _Float16 h = (_Float16)v;            // RNE
    u16 u; __builtin_memcpy(&u, &h, 2); return u;
}
__device__ __forceinline__ float h2f(u16 u) {
    _Float16 h; __builtin_memcpy(&h, &u, 2); return (float)h;
}
// fp16 2-way split: v ~= h + l to 2^-22 relative
__device__ __forceinline__ void split2(float v, u16& h, u16& l) {
    h = f2h(v);
    float r = v - h2f(h);
    l = f2h(r);
}
__device__ __forceinline__ unsigned pk(u16 a, u16 b) {
    return (unsigned)a | ((unsigned)b << 16);
}
__device__ __forceinline__ void store_planes(u16* base, size_t ps, size_t off, float v) {
    u16 h, l; split2(v, h, l);
    base[off] = h; base[ps + off] = l;
}
__device__ __forceinline__ void gload16(const void* g, void* l) {
    __builtin_amdgcn_global_load_lds(
        (const __attribute__((address_space(1))) void*)g,
        (__attribute__((address_space(3))) void*)l, 16, 0, 0);
}

// ---------------- CSR build (verified R1-R10) ----------------

__global__ void zero_kernel(int* __restrict__ p, int n) {
    int i = blockIdx.x * blockDim.x + threadIdx.x;
    if (i < n) p[i] = 0;
}
__global__ void hist_kernel(const int* __restrict__ dst, int* __restrict__ counts, int E) {
    int e = blockIdx.x * blockDim.x + threadIdx.x;
    if (e < E) atomicAdd(&counts[dst[e]], 1);
}
__global__ void scan_kernel(const int* __restrict__ counts, int* __restrict__ row_ptr, int n) {
    __shared__ int buf[1024];
    __shared__ int carry;
    const int tid = threadIdx.x;
    if (tid == 0) carry = 0;
    __syncthreads();
    for (int base = 0; base < n; base += 1024) {
        int i = base + tid;
        int v = (i < n) ? counts[i] : 0;
        buf[tid] = v;
        __syncthreads();
        for (int off = 1; off < 1024; off <<= 1) {
            int t = (tid >= off) ? buf[tid - off] : 0;
            __syncthreads();
            buf[tid] += t;
            __syncthreads();
        }
        if (i < n) row_ptr[i] = carry + buf[tid] - v;
        __syncthreads();
        if (tid == 0) carry += buf[1023];
        __syncthreads();
    }
    if (threadIdx.x == 0) row_ptr[n] = carry;
}
__global__ void fill_kernel(const int* __restrict__ src, const int* __restrict__ dst,
                            const int* __restrict__ row_ptr, int* __restrict__ cursor,
                            int* __restrict__ csr_src, int E) {
    int e = blockIdx.x * blockDim.x + threadIdx.x;
    if (e < E) {
        int d = dst[e];
        int p = atomicAdd(&cursor[d], 1);
        csr_src[row_ptr[d] + p] = src[e];
    }
}

// ---------------- fp32 -> 2 fp16 planes (rows padded w/ zero) ----------------
__global__ void split_rows(const float* __restrict__ src, u16* __restrict__ dst,
                           size_t pstride, int srcRows) {
    int row = blockIdx.x;
    int col = threadIdx.x;
    size_t off = (size_t)row * DD + col;
    float v = (row < srcRows) ? src[off] : 0.0f;
    store_planes(dst, pstride, off, v);
}

// ---------------- split-plane fp16 MFMA GEMM (R6 champion, K=256) ----------------
// C = epilogue(A @ W^T + bias). A,B as 2 fp16 planes (hi/lo), plane-major.
// 3-term product (hh, hl, lh) == fp32-grade (2^-22) precision.
template <int MODE>
__global__ __launch_bounds__(256, 4)
void gemm_planes(const u16* __restrict__ pA, size_t psA,
                 const u16* __restrict__ pB, size_t psB,
                 const float* __restrict__ bias1,
                 u16* __restrict__ outP, size_t psO, int M) {
    __shared__ u16 lds[16384];   // A: 2 planes x [128][32] = 8192; B same at +8192

    const int tid = threadIdx.x;
    const int lane = tid & 63;
    const int wv = tid >> 6;
    const int wr = wv >> 1;            // wave row 0..1 (64 rows)
    const int wc = wv & 1;             // wave col 0..1 (64 cols)
    const int frow = lane & 15;
    const int kg = lane >> 4;
    const int rowBase = blockIdx.x * BM;
    const int colBase = blockIdx.y * BN;

    // staging plan: 32 x 1KB wave-issues per tile, 8 per wave (0 bank conflicts).
    int offj[8]; int ldsj[8]; bool isBj[8];
#pragma unroll
    for (int j = 0; j < 8; ++j) {
        int q = wv * 8 + j;
        bool isB = q >= 16;
        int p = (q >> 3) & 1;
        int sub = q & 7;
        int row = sub * 16 + (lane >> 2);
        int chunk = (lane & 3) ^ ((row >> 1) & 3);
        int ps = isB ? (int)psB : (int)psA;
        int grow = (isB ? colBase : rowBase) + row;
        offj[j] = p * ps + grow * DD + chunk * 8;
        ldsj[j] = q * 512;
        isBj[j] = isB;
    }

    f32x4 acc[4][4] = {};

    for (int kc = 0; kc < DD; kc += BK) {
#pragma unroll
        for (int j = 0; j < 8; ++j)
            gload16((isBj[j] ? pB : pA) + offj[j] + kc, &lds[ldsj[j]]);
        __syncthreads();

        f16x8 af[2][4];
#pragma unroll
        for (int mf = 0; mf < 4; ++mf) {
            int row = wr * 64 + mf * 16 + frow;
            int off = row * 32 + ((kg ^ ((row >> 1) & 3)) * 8);
            af[0][mf] = *reinterpret_cast<const f16x8*>(&lds[off]);
            af[1][mf] = *reinterpret_cast<const f16x8*>(&lds[4096 + off]);
        }
#pragma unroll
        for (int nf = 0; nf < 4; ++nf) {
            int brow = wc * 64 + nf * 16 + frow;
            int boff = 8192 + brow * 32 + ((kg ^ ((brow >> 1) & 3)) * 8);
            f16x8 bh = *reinterpret_cast<const f16x8*>(&lds[boff]);
            f16x8 bl = *reinterpret_cast<const f16x8*>(&lds[boff + 4096]);
#pragma unroll
            for (int mf = 0; mf < 4; ++mf) {
                f32x4 c = acc[mf][nf];
                c = __builtin_amdgcn_mfma_f32_16x16x32_f16(af[0][mf], bh, c, 0, 0, 0);
                c = __builtin_amdgcn_mfma_f32_16x16x32_f16(af[0][mf], bl, c, 0, 0, 0);
                c = __builtin_amdgcn_mfma_f32_16x16x32_f16(af[1][mf], bh, c, 0, 0, 0);
                acc[mf][nf] = c;
            }
        }
        __syncthreads();
    }

#pragma unroll
    for (int nf = 0; nf < 4; ++nf) {
        int gc = colBase + wc * 64 + nf * 16 + frow;
        float b1v = bias1[gc];
#pragma unroll
        for (int mf = 0; mf < 4; ++mf) {
            f32x4 a = acc[mf][nf];
#pragma unroll
            for (int j = 0; j < 4; ++j) {
                int gr = rowBase + wr * 64 + mf * 16 + kg * 4 + j;
                if (gr < M) {
                    float v = a[j] + b1v;
                    size_t off = (size_t)gr * DD + gc;
                    if (MODE == MODE_RELU_P) store_planes(outP, psO, off, fmaxf(v, 0.0f));
                    else                     outP[off] = f2h(v);   // h: single fp16 plane
                }
            }
        }
    }
}

// ---------------- fully fused GRU kernel ----------------
// One pass over A=[msg|x] (k<256: msg vs Wih panels; k>=256: x vs Whh panels)
// against 3 B-panels (r,z,n). accr/accz span both halves; n-panel splits into
// accx (k<256) / acch (k>=256). Epilogue: full GRU update in-register.
// 512 threads = 8 waves (2 row x 4 col), per-wave 64x32 output tile.
template <bool FINAL>
__global__ __launch_bounds__(512, 2)
void gru_fused(const u16* __restrict__ pMsg, const u16* __restrict__ pX, size_t psA,
               const u16* __restrict__ pWih, const u16* __restrict__ pWhh, size_t psB,
               const float* __restrict__ bih, const float* __restrict__ bhh,
               float* __restrict__ outF, u16* __restrict__ outP, size_t psO, int M) {
    // LDS (u16 elems): A 2 planes x [128][32] at 0/4096 (16 KB);
    // B panel g (g=0,1,2) at 8192+g*8192: hi, +4096 lo (48 KB). Total 64 KB.
    __shared__ u16 lds[32768];

    const int tid = threadIdx.x;
    const int lane = tid & 63;
    const int wv = tid >> 6;           // 0..7
    const int wr = wv >> 2;            // 0..1 (64-row half)
    const int wc = wv & 3;             // 0..3 (32-col quarter)
    const int frow = lane & 15;
    const int kg = lane >> 4;
    const int rowBase = blockIdx.x * BM;
    const int colBase = blockIdx.y * BN;

    // staging plan: 64 x 1KB wave-issues per k-iter, 8 per wave.
    // q = wv*8+j; q<16: A (plane q>>3, sub q&7); q>=16: qb=q-16 in [0,48):
    //   B panel qb>>4, within-panel plane (qb>>3)&1, sub qb&7.
    int offj[8]; int ldsj[8]; bool isBj[8];
#pragma unroll
    for (int j = 0; j < 8; ++j) {
        int q = wv * 8 + j;
        bool isB = q >= 16;
        int eoff, ldso;
        if (!isB) {
            int p = (q >> 3) & 1; int sub = q & 7;
            int row = sub * 16 + (lane >> 2);
            int chunk = (lane & 3) ^ ((row >> 1) & 3);
            eoff = p * (int)psA + (rowBase + row) * DD + chunk * 8;
            ldso = q * 512;
        } else {
            int qb = q - 16;                 // 0..47
            int g = qb >> 4;                 // panel (gate) 0..2
            int p = (qb >> 3) & 1; int sub = qb & 7;
            int row = sub * 16 + (lane >> 2);
            int chunk = (lane & 3) ^ ((row >> 1) & 3);
            eoff = p * (int)psB + (g * 256 + colBase + row) * DD + chunk * 8;
            ldso = 8192 + qb * 512;
        }
        offj[j] = eoff; ldsj[j] = ldso; isBj[j] = isB;
    }

    f32x4 accr[4][2] = {};
    f32x4 accz[4][2] = {};
    f32x4 accx[4][2] = {};
    f32x4 acch[4][2] = {};

    // half = 0: A=msg, B=Wih, n-panel -> accx ; half = 1: A=x, B=Whh, n-panel -> acch
#pragma unroll
    for (int half = 0; half < 2; ++half) {
        const u16* Ab = half ? pX : pMsg;
        const u16* Bb = half ? pWhh : pWih;
        for (int kc = 0; kc < DD; kc += BK) {
#pragma unroll
            for (int j = 0; j < 8; ++j)
                gload16((isBj[j] ? Bb : Ab) + offj[j] + kc, &lds[ldsj[j]]);
            __syncthreads();

            f16x8 af[2][4];
#pragma unroll
            for (int mf = 0; mf < 4; ++mf) {
                int row = wr * 64 + mf * 16 + frow;
                int off = row * 32 + ((kg ^ ((row >> 1) & 3)) * 8);
                af[0][mf] = *reinterpret_cast<const f16x8*>(&lds[off]);
                af[1][mf] = *reinterpret_cast<const f16x8*>(&lds[4096 + off]);
            }
#pragma unroll
            for (int g = 0; g < 3; ++g) {
#pragma unroll
                for (int nf = 0; nf < 2; ++nf) {
                    int brow = wc * 32 + nf * 16 + frow;
                    int boff = 8192 + g * 8192 + brow * 32 + ((kg ^ ((brow >> 1) & 3)) * 8);
                    f16x8 bh = *reinterpret_cast<const f16x8*>(&lds[boff]);
                    f16x8 bl = *reinterpret_cast<const f16x8*>(&lds[boff + 4096]);
#pragma unroll
                    for (int mf = 0; mf < 4; ++mf) {
                        f32x4 c = (g == 0) ? accr[mf][nf]
                                : (g == 1) ? accz[mf][nf]
                                : (half == 0) ? accx[mf][nf] : acch[mf][nf];
                        c = __builtin_amdgcn_mfma_f32_16x16x32_f16(af[0][mf], bh, c, 0, 0, 0);
                        c = __builtin_amdgcn_mfma_f32_16x16x32_f16(af[0][mf], bl, c, 0, 0, 0);
                        c = __builtin_amdgcn_mfma_f32_16x16x32_f16(af[1][mf], bh, c, 0, 0, 0);
                        if (g == 0)      accr[mf][nf] = c;
                        else if (g == 1) accz[mf][nf] = c;
                        else if (half == 0) accx[mf][nf] = c;
                        else                acch[mf][nf] = c;
                    }
                }
            }
            __syncthreads();
        }
    }

    // epilogue: full GRU update
#pragma unroll
    for (int nf = 0; nf < 2; ++nf) {
        int gc = colBase + wc * 32 + nf * 16 + frow;
        float br = bih[gc] + bhh[gc];
        float bz = bih[256 + gc] + bhh[256 + gc];
        float bx = bih[512 + gc];
        float bh = bhh[512 + gc];
#pragma unroll
        for (int mf = 0; mf < 4; ++mf) {
#pragma unroll
            for (int j = 0; j < 4; ++j) {
                int gr = rowBase + wr * 64 + mf * 16 + kg * 4 + j;
                if (gr < M) {
                    size_t off = (size_t)gr * DD + gc;
                    float r = sigmoidf_(accr[mf][nf][j] + br);
                    float z = sigmoidf_(accz[mf][nf][j] + bz);
                    float T = tanhf(accx[mf][nf][j] + bx + r * (acch[mf][nf][j] + bh));
                    float x = h2f(pX[off]) + h2f(pX[psA + off]);
                    float o = (1.0f - z) * T + z * x;
                    if (FINAL) outF[off] = o;
                    else       store_planes(outP, psO, off, o);
                }
            }
        }
    }
}

// ---------------- segment sum (gather over fp16 h table) -> msg planes ----------------
__global__ __launch_bounds__(256)
void segsum_kernel(const u16* __restrict__ hp, const int* __restrict__ row_ptr,
                   const int* __restrict__ csr_src, u16* __restrict__ msgP,
                   size_t ps, int n) {
    int node = blockIdx.x * 4 + threadIdx.y;
    if (node >= n) return;
    int d4 = threadIdx.x * 4;
    int s = row_ptr[node];
    int e = row_ptr[node + 1];
    float4 acc = make_float4(0.f, 0.f, 0.f, 0.f);
    for (int j = s; j < e; ++j) {
        int sn = csr_src[j];
        f16x4 v = *reinterpret_cast<const f16x4*>(&hp[(size_t)sn * DD + d4]);
        acc.x += (float)v[0]; acc.y += (float)v[1];
        acc.z += (float)v[2]; acc.w += (float)v[3];
    }
    size_t off = (size_t)node * DD + d4;
    u16 h0,l0,h1,l1,h2,l2,h3,l3;
    split2(acc.x, h0,l0); split2(acc.y, h1,l1);
    split2(acc.z, h2,l2); split2(acc.w, h3,l3);
    *reinterpret_cast<uint2*>(&msgP[off])      = make_uint2(pk(h0,h1), pk(h2,h3));
    *reinterpret_cast<uint2*>(&msgP[ps + off]) = make_uint2(pk(l0,l1), pk(l2,l3));
}

// ---------------- launch ----------------

extern "C" void kernel_launch(void* const* d_in, const int* in_sizes, int n_in,
                              void* d_out, int out_size, void* d_ws, size_t ws_size,
                              hipStream_t stream) {
    const float* x0  = (const float*)d_in[0];
    const float* W1  = (const float*)d_in[1];
    const float* b1  = (const float*)d_in[2];
    const float* W2  = (const float*)d_in[3];
    const float* b2  = (const float*)d_in[4];
    const float* Wih = (const float*)d_in[5];
    const float* bih = (const float*)d_in[6];
    const float* Whh = (const float*)d_in[7];
    const float* bhh = (const float*)d_in[8];
    const int*   src = (const int*)d_in[9];
    const int*   dst = (const int*)d_in[10];

    // workspace layout (~211.3 MB — proven footprint)
    char* ws = (char*)d_ws;
    const size_t PSA = (size_t)NNP * DD;              // elems per activation plane
    const size_t SP  = PSA * 2 * sizeof(u16);         // 51.25 MB (2 fp16 planes)
    const size_t NB  = PSA * sizeof(float);           // 51.25 MB
    const size_t PSW2 = (size_t)DD * DD;              // 65536
    const size_t PSW3 = (size_t)3 * DD * DD;          // 196608
    u16* XP0   = (u16*)(ws);                          // x planes (even steps)
    u16* XP1   = (u16*)(ws + SP);                     // x planes (odd steps)
    u16* TP    = (u16*)(ws + 2 * SP);                 // t1 planes, then msg planes
    u16* HP    = (u16*)(ws + 3 * SP);                 // h fp16 plane
    u16* W1P   = (u16*)(ws + 3 * SP + NB);
    u16* W2P   = W1P + 2 * PSW2;
    u16* WIHP  = W2P + 2 * PSW2;
    u16* WHHP  = WIHP + 2 * PSW3;
    int* counts  = (int*)(WHHP + 2 * PSW3);
    int* cursor  = counts + NN;
    int* row_ptr = cursor + NN;                       // NN+1 ints
    int* csr     = row_ptr + NN + 8;                  // NE ints
    const size_t needed = 3 * SP + NB + (4 * PSW2 + 4 * PSW3) * sizeof(u16)
                        + (size_t)(2 * NN + NN + 9 + NE) * sizeof(int);
    if (ws_size < needed) return;   // clean fail instead of OOB crash

    float* FOUT = (float*)d_out;

    // CSR build
    zero_kernel<<<(2 * NN + 255) / 256, 256, 0, stream>>>(counts, 2 * NN);
    hist_kernel<<<(NE + 255) / 256, 256, 0, stream>>>(dst, counts, NE);
    scan_kernel<<<1, 1024, 0, stream>>>(counts, row_ptr, NN);
    fill_kernel<<<(NE + 255) / 256, 256, 0, stream>>>(src, dst, row_ptr, cursor, csr, NE);

    // pre-split weights (once) and x0 -> XP0
    split_rows<<<DD, 256, 0, stream>>>(W1, W1P, PSW2, DD);
    split_rows<<<DD, 256, 0, stream>>>(W2, W2P, PSW2, DD);
    split_rows<<<3 * DD, 256, 0, stream>>>(Wih, WIHP, PSW3, 3 * DD);
    split_rows<<<3 * DD, 256, 0, stream>>>(Whh, WHHP, PSW3, 3 * DD);
    split_rows<<<NNP, 256, 0, stream>>>(x0, XP0, PSA, NN);

    const dim3 grid(NNP / BM, DD / BN);   // 391 x 2

    for (int s = 0; s < NSTEPS; ++s) {
        u16* XPc = (s & 1) ? XP1 : XP0;
        u16* XPn = (s & 1) ? XP0 : XP1;

        // t1 = ReLU(x @ W1^T + b1) -> TP planes
        gemm_planes<MODE_RELU_P><<<grid, 256, 0, stream>>>(
            XPc, PSA, W1P, PSW2, b1, TP, PSA, NN);
        // h = t1 @ W2^T + b2 -> HP (single fp16 plane)
        gemm_planes<MODE_PLAIN_H><<<grid, 256, 0, stream>>>(
            TP, PSA, W2P, PSW2, b2, HP, 0, NN);
        // msg = segment_sum(h[src], dst) -> TP planes (t1 dead)
        segsum_kernel<<<dim3((NN + 3) / 4), dim3(64, 4), 0, stream>>>(
            HP, row_ptr, csr, TP, PSA, NN);
        // full GRU update in one kernel -> x_next planes (final: fp32 d_out)
        if (s < NSTEPS - 1) {
            gru_fused<false><<<grid, 512, 0, stream>>>(
                TP, XPc, PSA, WIHP, WHHP, PSW3, bih, bhh,
                nullptr, XPn, PSA, NN);
        } else {
            gru_fused<true><<<grid, 512, 0, stream>>>(
                TP, XPc, PSA, WIHP, WHHP, PSW3, bih, bhh,
                FOUT, nullptr, 0, NN);
        }
    }
}

// Round 12
// 2447.360 us; speedup vs baseline: 1.4320x; 1.0062x over previous
//
#include <hip/hip_runtime.h>
#include <hip/hip_bf16.h>
#include <math.h>

// Problem constants
#define NN 50000
#define NNP 50048       // rows padded to multiple of BM=128
#define NE 800000
#define DD 256
#define NSTEPS 6

// GEMM tiling (R6-proven champion geometry)
#define BM 128
#define BN 128
#define BK 32

typedef unsigned short u16;
typedef _Float16 f16x8 __attribute__((ext_vector_type(8)));
typedef _Float16 f16x4 __attribute__((ext_vector_type(4)));
typedef float f32x4 __attribute__((ext_vector_type(4)));

#define MODE_RELU_P  0   // relu(v+b1) -> 2 planes
#define MODE_PLAIN_H 1   // v+b1 -> single fp16 plane

#define FENCE() asm volatile("" ::: "memory")

__device__ __forceinline__ float sigmoidf_(float v) {
    return 1.0f / (1.0f + expf(-v));
}
__device__ __forceinline__ u16 f2h(float v) {
    _Float16 h = (_Float16)v;            // RNE
    u16 u; __builtin_memcpy(&u, &h, 2); return u;
}
__device__ __forceinline__ float h2f(u16 u) {
    _Float16 h; __builtin_memcpy(&h, &u, 2); return (float)h;
}
// fp16 2-way split: v ~= h + l to 2^-22 relative
__device__ __forceinline__ void split2(float v, u16& h, u16& l) {
    h = f2h(v);
    float r = v - h2f(h);
    l = f2h(r);
}
__device__ __forceinline__ unsigned pk(u16 a, u16 b) {
    return (unsigned)a | ((unsigned)b << 16);
}
__device__ __forceinline__ void store_planes(u16* base, size_t ps, size_t off, float v) {
    u16 h, l; split2(v, h, l);
    base[off] = h; base[ps + off] = l;
}
__device__ __forceinline__ void gload16(const void* g, void* l) {
    __builtin_amdgcn_global_load_lds(
        (const __attribute__((address_space(1))) void*)g,
        (__attribute__((address_space(3))) void*)l, 16, 0, 0);
}

// ---------------- CSR build (verified R1-R11) ----------------

__global__ void zero_kernel(int* __restrict__ p, int n) {
    int i = blockIdx.x * blockDim.x + threadIdx.x;
    if (i < n) p[i] = 0;
}
__global__ void hist_kernel(const int* __restrict__ dst, int* __restrict__ counts, int E) {
    int e = blockIdx.x * blockDim.x + threadIdx.x;
    if (e < E) atomicAdd(&counts[dst[e]], 1);
}
__global__ void scan_kernel(const int* __restrict__ counts, int* __restrict__ row_ptr, int n) {
    __shared__ int buf[1024];
    __shared__ int carry;
    const int tid = threadIdx.x;
    if (tid == 0) carry = 0;
    __syncthreads();
    for (int base = 0; base < n; base += 1024) {
        int i = base + tid;
        int v = (i < n) ? counts[i] : 0;
        buf[tid] = v;
        __syncthreads();
        for (int off = 1; off < 1024; off <<= 1) {
            int t = (tid >= off) ? buf[tid - off] : 0;
            __syncthreads();
            buf[tid] += t;
            __syncthreads();
        }
        if (i < n) row_ptr[i] = carry + buf[tid] - v;
        __syncthreads();
        if (tid == 0) carry += buf[1023];
        __syncthreads();
    }
    if (threadIdx.x == 0) row_ptr[n] = carry;
}
__global__ void fill_kernel(const int* __restrict__ src, const int* __restrict__ dst,
                            const int* __restrict__ row_ptr, int* __restrict__ cursor,
                            int* __restrict__ csr_src, int E) {
    int e = blockIdx.x * blockDim.x + threadIdx.x;
    if (e < E) {
        int d = dst[e];
        int p = atomicAdd(&cursor[d], 1);
        csr_src[row_ptr[d] + p] = src[e];
    }
}

// ---------------- fp32 -> 2 fp16 planes (rows padded w/ zero) ----------------
__global__ void split_rows(const float* __restrict__ src, u16* __restrict__ dst,
                           size_t pstride, int srcRows) {
    int row = blockIdx.x;
    int col = threadIdx.x;
    size_t off = (size_t)row * DD + col;
    float v = (row < srcRows) ? src[off] : 0.0f;
    store_planes(dst, pstride, off, v);
}

// ---------------- split-plane fp16 MFMA GEMM (R6 champion, K=256) ----------------
// C = epilogue(A @ W^T + bias). A,B as 2 fp16 planes (hi/lo), plane-major.
// 3-term product (hh, hl, lh) == fp32-grade (2^-22) precision.
template <int MODE>
__global__ __launch_bounds__(256, 4)
void gemm_planes(const u16* __restrict__ pA, size_t psA,
                 const u16* __restrict__ pB, size_t psB,
                 const float* __restrict__ bias1,
                 u16* __restrict__ outP, size_t psO, int M) {
    __shared__ u16 lds[16384];   // A: 2 planes x [128][32] = 8192; B same at +8192

    const int tid = threadIdx.x;
    const int lane = tid & 63;
    const int wv = tid >> 6;
    const int wr = wv >> 1;            // wave row 0..1 (64 rows)
    const int wc = wv & 1;             // wave col 0..1 (64 cols)
    const int frow = lane & 15;
    const int kg = lane >> 4;
    const int rowBase = blockIdx.x * BM;
    const int colBase = blockIdx.y * BN;

    // staging plan: 32 x 1KB wave-issues per tile, 8 per wave (0 bank conflicts).
    int offj[8]; int ldsj[8]; bool isBj[8];
#pragma unroll
    for (int j = 0; j < 8; ++j) {
        int q = wv * 8 + j;
        bool isB = q >= 16;
        int p = (q >> 3) & 1;
        int sub = q & 7;
        int row = sub * 16 + (lane >> 2);
        int chunk = (lane & 3) ^ ((row >> 1) & 3);
        int ps = isB ? (int)psB : (int)psA;
        int grow = (isB ? colBase : rowBase) + row;
        offj[j] = p * ps + grow * DD + chunk * 8;
        ldsj[j] = q * 512;
        isBj[j] = isB;
    }

    f32x4 acc[4][4] = {};

    for (int kc = 0; kc < DD; kc += BK) {
#pragma unroll
        for (int j = 0; j < 8; ++j)
            gload16((isBj[j] ? pB : pA) + offj[j] + kc, &lds[ldsj[j]]);
        __syncthreads();

        f16x8 af[2][4];
#pragma unroll
        for (int mf = 0; mf < 4; ++mf) {
            int row = wr * 64 + mf * 16 + frow;
            int off = row * 32 + ((kg ^ ((row >> 1) & 3)) * 8);
            af[0][mf] = *reinterpret_cast<const f16x8*>(&lds[off]);
            af[1][mf] = *reinterpret_cast<const f16x8*>(&lds[4096 + off]);
        }
#pragma unroll
        for (int nf = 0; nf < 4; ++nf) {
            int brow = wc * 64 + nf * 16 + frow;
            int boff = 8192 + brow * 32 + ((kg ^ ((brow >> 1) & 3)) * 8);
            f16x8 bh = *reinterpret_cast<const f16x8*>(&lds[boff]);
            f16x8 bl = *reinterpret_cast<const f16x8*>(&lds[boff + 4096]);
#pragma unroll
            for (int mf = 0; mf < 4; ++mf) {
                f32x4 c = acc[mf][nf];
                c = __builtin_amdgcn_mfma_f32_16x16x32_f16(af[0][mf], bh, c, 0, 0, 0);
                c = __builtin_amdgcn_mfma_f32_16x16x32_f16(af[0][mf], bl, c, 0, 0, 0);
                c = __builtin_amdgcn_mfma_f32_16x16x32_f16(af[1][mf], bh, c, 0, 0, 0);
                acc[mf][nf] = c;
            }
        }
        __syncthreads();
    }

#pragma unroll
    for (int nf = 0; nf < 4; ++nf) {
        int gc = colBase + wc * 64 + nf * 16 + frow;
        float b1v = bias1[gc];
#pragma unroll
        for (int mf = 0; mf < 4; ++mf) {
            f32x4 a = acc[mf][nf];
#pragma unroll
            for (int j = 0; j < 4; ++j) {
                int gr = rowBase + wr * 64 + mf * 16 + kg * 4 + j;
                if (gr < M) {
                    float v = a[j] + b1v;
                    size_t off = (size_t)gr * DD + gc;
                    if (MODE == MODE_RELU_P) store_planes(outP, psO, off, fmaxf(v, 0.0f));
                    else                     outP[off] = f2h(v);   // h: single fp16 plane
                }
            }
        }
    }
}

// ---------------- fully fused GRU kernel, counted-vmcnt pipelined ----------------
// One pass over A=[msg|x] (t<8: msg vs Wih panels; t>=8: x vs Whh panels)
// against 3 B-panels (r,z,n). accr/accz span both halves; n-panel splits into
// accx (t<8) / acch (t>=8). Epilogue: full GRU update in-register.
// 512 threads = 8 waves (2 row x 4 col), per-wave 64x32 output tile.
// Pipeline: A double-buffered (2-deep prefetch, hides HBM ~900cy under 2 MFMA
// phases); B single-buffered (1-deep, L2-hot weights ~250cy under 1 phase).
// Per-wave-uniform staging (2 A + 6 B issues) makes vmcnt counting exact:
// at each loop head, outstanding FIFO = {A(t):2, B(t):6, A(t+1):2} -> vmcnt(2).
template <bool FINAL>
__global__ __launch_bounds__(512, 2)
void gru_fused(const u16* __restrict__ pMsg, const u16* __restrict__ pX, size_t psA,
               const u16* __restrict__ pWih, const u16* __restrict__ pWhh, size_t psB,
               const float* __restrict__ bih, const float* __restrict__ bhh,
               float* __restrict__ outF, u16* __restrict__ outP, size_t psO, int M) {
    // LDS (u16 elems), 80 KB total:
    //   A buf0 at 0, buf1 at 8192 (each: hi [128][32] + lo, 16 KB)
    //   B panels at 16384: gate g at +g*8192 (hi, +4096 lo), 48 KB
    __shared__ u16 lds[40960];

    const int tid = threadIdx.x;
    const int lane = tid & 63;
    const int wv = tid >> 6;           // 0..7
    const int wr = wv >> 2;            // 0..1 (64-row half)
    const int wc = wv & 3;             // 0..3 (32-col quarter)
    const int frow = lane & 15;
    const int kg = lane >> 4;
    const int rowBase = blockIdx.x * BM;
    const int colBase = blockIdx.y * BN;

    // per-wave-uniform staging maps: 2 A issues (jA: plane), 6 B issues (jB: gate*2+plane).
    // A: q = jA*8 + wv -> plane jA, rows [wv*16, wv*16+16)
    // B: qb = jB*8 + wv -> gate jB>>1, plane jB&1, rows [wv*16, wv*16+16)
    int offA[2]; int ldsA[2];
    int offB[6]; int ldsB[6];
    {
        int row = wv * 16 + (lane >> 2);
        int chunk = (lane & 3) ^ ((row >> 1) & 3);
#pragma unroll
        for (int jA = 0; jA < 2; ++jA) {
            offA[jA] = jA * (int)psA + (rowBase + row) * DD + chunk * 8;
            ldsA[jA] = jA * 4096 + wv * 512;            // buf-relative
        }
#pragma unroll
        for (int jB = 0; jB < 6; ++jB) {
            int g = jB >> 1, p = jB & 1;
            offB[jB] = p * (int)psB + (g * 256 + colBase + row) * DD + chunk * 8;
            ldsB[jB] = 16384 + g * 8192 + p * 4096 + wv * 512;
        }
    }

    auto STAGE_A = [&](int buf, int t) {     // t in [0,16)
        const u16* Ab = (t < 8) ? pMsg : pX;
        int kc = (t & 7) * BK;
#pragma unroll
        for (int jA = 0; jA < 2; ++jA)
            gload16(Ab + offA[jA] + kc, &lds[buf * 8192 + ldsA[jA]]);
    };
    auto STAGE_B = [&](int t) {
        const u16* Bb = (t < 8) ? pWih : pWhh;
        int kc = (t & 7) * BK;
#pragma unroll
        for (int jB = 0; jB < 6; ++jB)
            gload16(Bb + offB[jB] + kc, &lds[ldsB[jB]]);
    };

    f32x4 accr[4][2] = {};
    f32x4 accz[4][2] = {};
    f32x4 accx[4][2] = {};
    f32x4 acch[4][2] = {};

    const int NT = 16;
    // prologue: A(0), B(0), then A(1) — order matters for FIFO vmcnt counting
    STAGE_A(0, 0);
    STAGE_B(0);
    FENCE();
    STAGE_A(1, 1);
    FENCE();

    for (int t = 0; t < NT; ++t) {
        const int cur = t & 1;
        if (t + 1 < NT) {
            asm volatile("s_waitcnt vmcnt(2)" ::: "memory");  // A(t),B(t) done; A(t+1) flying
        } else {
            asm volatile("s_waitcnt vmcnt(0)" ::: "memory");
        }
        __builtin_amdgcn_s_barrier();

        const u16* LA = &lds[cur * 8192];
        f16x8 af[2][4];
#pragma unroll
        for (int mf = 0; mf < 4; ++mf) {
            int row = wr * 64 + mf * 16 + frow;
            int off = row * 32 + ((kg ^ ((row >> 1) & 3)) * 8);
            af[0][mf] = *reinterpret_cast<const f16x8*>(&LA[off]);
            af[1][mf] = *reinterpret_cast<const f16x8*>(&LA[4096 + off]);
        }
        const bool firstHalf = (t < 8);
#pragma unroll
        for (int g = 0; g < 3; ++g) {
#pragma unroll
            for (int nf = 0; nf < 2; ++nf) {
                int brow = wc * 32 + nf * 16 + frow;
                int boff = 16384 + g * 8192 + brow * 32 + ((kg ^ ((brow >> 1) & 3)) * 8);
                f16x8 bh = *reinterpret_cast<const f16x8*>(&lds[boff]);
                f16x8 bl = *reinterpret_cast<const f16x8*>(&lds[boff + 4096]);
#pragma unroll
                for (int mf = 0; mf < 4; ++mf) {
                    f32x4 c = (g == 0) ? accr[mf][nf]
                            : (g == 1) ? accz[mf][nf]
                            : firstHalf ? accx[mf][nf] : acch[mf][nf];
                    c = __builtin_amdgcn_mfma_f32_16x16x32_f16(af[0][mf], bh, c, 0, 0, 0);
                    c = __builtin_amdgcn_mfma_f32_16x16x32_f16(af[0][mf], bl, c, 0, 0, 0);
                    c = __builtin_amdgcn_mfma_f32_16x16x32_f16(af[1][mf], bh, c, 0, 0, 0);
                    if (g == 0)      accr[mf][nf] = c;
                    else if (g == 1) accz[mf][nf] = c;
                    else if (firstHalf) accx[mf][nf] = c;
                    else                acch[mf][nf] = c;
                }
            }
        }
        __builtin_amdgcn_s_barrier();   // all waves done reading B(t) and A buf cur

        if (t + 1 < NT) {
            STAGE_B(t + 1);             // 6 issues: lands during next loop-back + wait
            FENCE();
            if (t + 2 < NT) STAGE_A(cur, t + 2);   // 2 issues: 2-deep, into just-freed buf
            FENCE();
        }
    }

    // epilogue: full GRU update
#pragma unroll
    for (int nf = 0; nf < 2; ++nf) {
        int gc = colBase + wc * 32 + nf * 16 + frow;
        float br = bih[gc] + bhh[gc];
        float bz = bih[256 + gc] + bhh[256 + gc];
        float bx = bih[512 + gc];
        float bh = bhh[512 + gc];
#pragma unroll
        for (int mf = 0; mf < 4; ++mf) {
#pragma unroll
            for (int j = 0; j < 4; ++j) {
                int gr = rowBase + wr * 64 + mf * 16 + kg * 4 + j;
                if (gr < M) {
                    size_t off = (size_t)gr * DD + gc;
                    float r = sigmoidf_(accr[mf][nf][j] + br);
                    float z = sigmoidf_(accz[mf][nf][j] + bz);
                    float T = tanhf(accx[mf][nf][j] + bx + r * (acch[mf][nf][j] + bh));
                    float x = h2f(pX[off]) + h2f(pX[psA + off]);
                    float o = (1.0f - z) * T + z * x;
                    if (FINAL) outF[off] = o;
                    else       store_planes(outP, psO, off, o);
                }
            }
        }
    }
}

// ---------------- segment sum (gather over fp16 h table) -> msg planes ----------------
__global__ __launch_bounds__(256)
void segsum_kernel(const u16* __restrict__ hp, const int* __restrict__ row_ptr,
                   const int* __restrict__ csr_src, u16* __restrict__ msgP,
                   size_t ps, int n) {
    int node = blockIdx.x * 4 + threadIdx.y;
    if (node >= n) return;
    int d4 = threadIdx.x * 4;
    int s = row_ptr[node];
    int e = row_ptr[node + 1];
    float4 acc = make_float4(0.f, 0.f, 0.f, 0.f);
    for (int j = s; j < e; ++j) {
        int sn = csr_src[j];
        f16x4 v = *reinterpret_cast<const f16x4*>(&hp[(size_t)sn * DD + d4]);
        acc.x += (float)v[0]; acc.y += (float)v[1];
        acc.z += (float)v[2]; acc.w += (float)v[3];
    }
    size_t off = (size_t)node * DD + d4;
    u16 h0,l0,h1,l1,h2,l2,h3,l3;
    split2(acc.x, h0,l0); split2(acc.y, h1,l1);
    split2(acc.z, h2,l2); split2(acc.w, h3,l3);
    *reinterpret_cast<uint2*>(&msgP[off])      = make_uint2(pk(h0,h1), pk(h2,h3));
    *reinterpret_cast<uint2*>(&msgP[ps + off]) = make_uint2(pk(l0,l1), pk(l2,l3));
}

// ---------------- launch ----------------

extern "C" void kernel_launch(void* const* d_in, const int* in_sizes, int n_in,
                              void* d_out, int out_size, void* d_ws, size_t ws_size,
                              hipStream_t stream) {
    const float* x0  = (const float*)d_in[0];
    const float* W1  = (const float*)d_in[1];
    const float* b1  = (const float*)d_in[2];
    const float* W2  = (const float*)d_in[3];
    const float* b2  = (const float*)d_in[4];
    const float* Wih = (const float*)d_in[5];
    const float* bih = (const float*)d_in[6];
    const float* Whh = (const float*)d_in[7];
    const float* bhh = (const float*)d_in[8];
    const int*   src = (const int*)d_in[9];
    const int*   dst = (const int*)d_in[10];

    // workspace layout (~211.3 MB — proven footprint)
    char* ws = (char*)d_ws;
    const size_t PSA = (size_t)NNP * DD;              // elems per activation plane
    const size_t SP  = PSA * 2 * sizeof(u16);         // 51.25 MB (2 fp16 planes)
    const size_t NB  = PSA * sizeof(float);           // 51.25 MB
    const size_t PSW2 = (size_t)DD * DD;              // 65536
    const size_t PSW3 = (size_t)3 * DD * DD;          // 196608
    u16* XP0   = (u16*)(ws);                          // x planes (even steps)
    u16* XP1   = (u16*)(ws + SP);                     // x planes (odd steps)
    u16* TP    = (u16*)(ws + 2 * SP);                 // t1 planes, then msg planes
    u16* HP    = (u16*)(ws + 3 * SP);                 // h fp16 plane
    u16* W1P   = (u16*)(ws + 3 * SP + NB);
    u16* W2P   = W1P + 2 * PSW2;
    u16* WIHP  = W2P + 2 * PSW2;
    u16* WHHP  = WIHP + 2 * PSW3;
    int* counts  = (int*)(WHHP + 2 * PSW3);
    int* cursor  = counts + NN;
    int* row_ptr = cursor + NN;                       // NN+1 ints
    int* csr     = row_ptr + NN + 8;                  // NE ints
    const size_t needed = 3 * SP + NB + (4 * PSW2 + 4 * PSW3) * sizeof(u16)
                        + (size_t)(2 * NN + NN + 9 + NE) * sizeof(int);
    if (ws_size < needed) return;   // clean fail instead of OOB crash

    float* FOUT = (float*)d_out;

    // CSR build
    zero_kernel<<<(2 * NN + 255) / 256, 256, 0, stream>>>(counts, 2 * NN);
    hist_kernel<<<(NE + 255) / 256, 256, 0, stream>>>(dst, counts, NE);
    scan_kernel<<<1, 1024, 0, stream>>>(counts, row_ptr, NN);
    fill_kernel<<<(NE + 255) / 256, 256, 0, stream>>>(src, dst, row_ptr, cursor, csr, NE);

    // pre-split weights (once) and x0 -> XP0
    split_rows<<<DD, 256, 0, stream>>>(W1, W1P, PSW2, DD);
    split_rows<<<DD, 256, 0, stream>>>(W2, W2P, PSW2, DD);
    split_rows<<<3 * DD, 256, 0, stream>>>(Wih, WIHP, PSW3, 3 * DD);
    split_rows<<<3 * DD, 256, 0, stream>>>(Whh, WHHP, PSW3, 3 * DD);
    split_rows<<<NNP, 256, 0, stream>>>(x0, XP0, PSA, NN);

    const dim3 grid(NNP / BM, DD / BN);   // 391 x 2

    for (int s = 0; s < NSTEPS; ++s) {
        u16* XPc = (s & 1) ? XP1 : XP0;
        u16* XPn = (s & 1) ? XP0 : XP1;

        // t1 = ReLU(x @ W1^T + b1) -> TP planes
        gemm_planes<MODE_RELU_P><<<grid, 256, 0, stream>>>(
            XPc, PSA, W1P, PSW2, b1, TP, PSA, NN);
        // h = t1 @ W2^T + b2 -> HP (single fp16 plane)
        gemm_planes<MODE_PLAIN_H><<<grid, 256, 0, stream>>>(
            TP, PSA, W2P, PSW2, b2, HP, 0, NN);
        // msg = segment_sum(h[src], dst) -> TP planes (t1 dead)
        segsum_kernel<<<dim3((NN + 3) / 4), dim3(64, 4), 0, stream>>>(
            HP, row_ptr, csr, TP, PSA, NN);
        // full GRU update in one kernel -> x_next planes (final: fp32 d_out)
        if (s < NSTEPS - 1) {
            gru_fused<false><<<grid, 512, 0, stream>>>(
                TP, XPc, PSA, WIHP, WHHP, PSW3, bih, bhh,
                nullptr, XPn, PSA, NN);
        } else {
            gru_fused<true><<<grid, 512, 0, stream>>>(
                TP, XPc, PSA, WIHP, WHHP, PSW3, bih, bhh,
                FOUT, nullptr, 0, NN);
        }
    }
}

// Round 13
// 2378.528 us; speedup vs baseline: 1.4734x; 1.0289x over previous
//
#include <hip/hip_runtime.h>
#include <hip/hip_bf16.h>
#include <math.h>

// Problem constants
#define NN 50000
#define NNP 50048       // rows padded to multiple of 128
#define NE 800000
#define DD 256
#define NSTEPS 6

#define BM 128
#define BN 128
#define BK 32

typedef unsigned short u16;
typedef _Float16 f16x8 __attribute__((ext_vector_type(8)));
typedef _Float16 f16x4 __attribute__((ext_vector_type(4)));
typedef float f32x4 __attribute__((ext_vector_type(4)));

__device__ __forceinline__ float sigmoidf_(float v) {
    return 1.0f / (1.0f + expf(-v));
}
__device__ __forceinline__ u16 f2h(float v) {
    _Float16 h = (_Float16)v;            // RNE
    u16 u; __builtin_memcpy(&u, &h, 2); return u;
}
__device__ __forceinline__ float h2f(u16 u) {
    _Float16 h; __builtin_memcpy(&h, &u, 2); return (float)h;
}
// fp16 2-way split: v ~= h + l to 2^-22 relative
__device__ __forceinline__ void split2(float v, u16& h, u16& l) {
    h = f2h(v);
    float r = v - h2f(h);
    l = f2h(r);
}
__device__ __forceinline__ unsigned pk(u16 a, u16 b) {
    return (unsigned)a | ((unsigned)b << 16);
}
__device__ __forceinline__ void store_planes(u16* base, size_t ps, size_t off, float v) {
    u16 h, l; split2(v, h, l);
    base[off] = h; base[ps + off] = l;
}
__device__ __forceinline__ void gload16(const void* g, void* l) {
    __builtin_amdgcn_global_load_lds(
        (const __attribute__((address_space(1))) void*)g,
        (__attribute__((address_space(3))) void*)l, 16, 0, 0);
}

// ---------------- CSR build (verified R1-R12) ----------------

__global__ void zero_kernel(int* __restrict__ p, int n) {
    int i = blockIdx.x * blockDim.x + threadIdx.x;
    if (i < n) p[i] = 0;
}
__global__ void hist_kernel(const int* __restrict__ dst, int* __restrict__ counts, int E) {
    int e = blockIdx.x * blockDim.x + threadIdx.x;
    if (e < E) atomicAdd(&counts[dst[e]], 1);
}
__global__ void scan_kernel(const int* __restrict__ counts, int* __restrict__ row_ptr, int n) {
    __shared__ int buf[1024];
    __shared__ int carry;
    const int tid = threadIdx.x;
    if (tid == 0) carry = 0;
    __syncthreads();
    for (int base = 0; base < n; base += 1024) {
        int i = base + tid;
        int v = (i < n) ? counts[i] : 0;
        buf[tid] = v;
        __syncthreads();
        for (int off = 1; off < 1024; off <<= 1) {
            int t = (tid >= off) ? buf[tid - off] : 0;
            __syncthreads();
            buf[tid] += t;
            __syncthreads();
        }
        if (i < n) row_ptr[i] = carry + buf[tid] - v;
        __syncthreads();
        if (tid == 0) carry += buf[1023];
        __syncthreads();
    }
    if (threadIdx.x == 0) row_ptr[n] = carry;
}
__global__ void fill_kernel(const int* __restrict__ src, const int* __restrict__ dst,
                            const int* __restrict__ row_ptr, int* __restrict__ cursor,
                            int* __restrict__ csr_src, int E) {
    int e = blockIdx.x * blockDim.x + threadIdx.x;
    if (e < E) {
        int d = dst[e];
        int p = atomicAdd(&cursor[d], 1);
        csr_src[row_ptr[d] + p] = src[e];
    }
}

// ---------------- fp32 -> 2 fp16 planes (rows padded w/ zero) ----------------
__global__ void split_rows(const float* __restrict__ src, u16* __restrict__ dst,
                           size_t pstride, int srcRows) {
    int row = blockIdx.x;
    int col = threadIdx.x;
    size_t off = (size_t)row * DD + col;
    float v = (row < srcRows) ? src[off] : 0.0f;
    store_planes(dst, pstride, off, v);
}

// ---------------- fused MLP: h = (ReLU(x@W1^T+b1))@W2^T + b2 -> fp16 ----------------
// Block: 32 rows x all 256 cols, 256 threads (4 waves; wave w = col quarter).
// Phase 1: t1 tile -> LDS fp16, chunk-XOR swizzled (no HBM round-trip).
// Phase 2: h from LDS t1 (2-term product: t1_h x (W2h + W2l)).
__global__ __launch_bounds__(256, 3)
void mlp_fused(const u16* __restrict__ pX, size_t psA,
               const u16* __restrict__ W1P, const u16* __restrict__ W2P, size_t psW,
               const float* __restrict__ b1, const float* __restrict__ b2,
               u16* __restrict__ HP, int M) {
    // LDS (u16): A 0..2047 (2 planes x [32][32]); W 2048..18431 (2 planes x [256][32]);
    // t1 18432..26623 ([32][256] fp16, chunk-XOR swizzle). 52 KB.
    __shared__ u16 lds[26624];
    const int T1B = 18432;

    const int tid = threadIdx.x;
    const int lane = tid & 63;
    const int wv = tid >> 6;           // col quarter 0..3
    const int frow = lane & 15;
    const int kg = lane >> 4;
    const int rowBase = blockIdx.x * 32;

    // staging maps: 36 x 1KB issues per k-iter, 9 per wave.
    // q = wv*9+j; q<4: A (plane q>>1, sub q&1); q>=4: W (qw=q-4: plane qw>>4, sub qw&15)
    int offj[9]; int ldsj[9]; bool isWj[9];
#pragma unroll
    for (int j = 0; j < 9; ++j) {
        int q = wv * 9 + j;
        int row, plane, ldso;
        bool isW = q >= 4;
        if (!isW) {
            plane = q >> 1; int sub = q & 1;
            row = sub * 16 + (lane >> 2);
            ldso = q * 512;
        } else {
            int qw = q - 4;
            plane = qw >> 4; int sub = qw & 15;
            row = sub * 16 + (lane >> 2);
            ldso = 2048 + qw * 512;
        }
        int chunk = (lane & 3) ^ ((row >> 1) & 3);
        offj[j] = plane * (int)(isW ? psW : psA) + ((isW ? 0 : rowBase) + row) * DD + chunk * 8;
        ldsj[j] = ldso;
        isWj[j] = isW;
    }

    // ---- phase 1: t1 = ReLU(x @ W1^T + b1) ----
    f32x4 acc1[2][4] = {};
    for (int kc = 0; kc < DD; kc += BK) {
#pragma unroll
        for (int j = 0; j < 9; ++j)
            gload16((isWj[j] ? W1P : pX) + offj[j] + kc, &lds[ldsj[j]]);
        __syncthreads();

        f16x8 af[2][2];
#pragma unroll
        for (int mf = 0; mf < 2; ++mf) {
            int row = mf * 16 + frow;
            int off = row * 32 + ((kg ^ ((row >> 1) & 3)) * 8);
            af[0][mf] = *reinterpret_cast<const f16x8*>(&lds[off]);
            af[1][mf] = *reinterpret_cast<const f16x8*>(&lds[1024 + off]);
        }
#pragma unroll
        for (int nf = 0; nf < 4; ++nf) {
            int brow = wv * 64 + nf * 16 + frow;
            int boff = 2048 + brow * 32 + ((kg ^ ((brow >> 1) & 3)) * 8);
            f16x8 bh = *reinterpret_cast<const f16x8*>(&lds[boff]);
            f16x8 bl = *reinterpret_cast<const f16x8*>(&lds[boff + 8192]);
#pragma unroll
            for (int mf = 0; mf < 2; ++mf) {
                f32x4 c = acc1[mf][nf];
                c = __builtin_amdgcn_mfma_f32_16x16x32_f16(af[0][mf], bh, c, 0, 0, 0);
                c = __builtin_amdgcn_mfma_f32_16x16x32_f16(af[0][mf], bl, c, 0, 0, 0);
                c = __builtin_amdgcn_mfma_f32_16x16x32_f16(af[1][mf], bh, c, 0, 0, 0);
                acc1[mf][nf] = c;
            }
        }
        __syncthreads();
    }

    // t1 -> LDS fp16 (swizzled: chunk index XOR (row&7))
#pragma unroll
    for (int nf = 0; nf < 4; ++nf) {
        int col = wv * 64 + nf * 16 + frow;
        float bb = b1[col];
        int c8 = col >> 3, ci = col & 7;
#pragma unroll
        for (int mf = 0; mf < 2; ++mf) {
#pragma unroll
            for (int j = 0; j < 4; ++j) {
                int row = mf * 16 + kg * 4 + j;
                float v = fmaxf(acc1[mf][nf][j] + bb, 0.0f);
                lds[T1B + row * 256 + ((c8 ^ (row & 7)) * 8) + ci] = f2h(v);
            }
        }
    }
    __syncthreads();

    // ---- phase 2: h = t1 @ W2^T + b2 ----
    f32x4 acc2[2][4] = {};
    for (int kc = 0; kc < DD; kc += BK) {
#pragma unroll
        for (int j = 0; j < 9; ++j)
            if (isWj[j]) gload16(W2P + offj[j] + kc, &lds[ldsj[j]]);
        __syncthreads();

        f16x8 at[2];
#pragma unroll
        for (int mf = 0; mf < 2; ++mf) {
            int row = mf * 16 + frow;
            int qc = (kc >> 3) + kg;   // logical chunk index 0..31
            at[mf] = *reinterpret_cast<const f16x8*>(
                &lds[T1B + row * 256 + ((qc ^ (row & 7)) * 8)]);
        }
#pragma unroll
        for (int nf = 0; nf < 4; ++nf) {
            int brow = wv * 64 + nf * 16 + frow;
            int boff = 2048 + brow * 32 + ((kg ^ ((brow >> 1) & 3)) * 8);
            f16x8 bh = *reinterpret_cast<const f16x8*>(&lds[boff]);
            f16x8 bl = *reinterpret_cast<const f16x8*>(&lds[boff + 8192]);
#pragma unroll
            for (int mf = 0; mf < 2; ++mf) {
                f32x4 c = acc2[mf][nf];
                c = __builtin_amdgcn_mfma_f32_16x16x32_f16(at[mf], bh, c, 0, 0, 0);
                c = __builtin_amdgcn_mfma_f32_16x16x32_f16(at[mf], bl, c, 0, 0, 0);
                acc2[mf][nf] = c;
            }
        }
        __syncthreads();
    }

    // h -> HP (single fp16 plane)
#pragma unroll
    for (int nf = 0; nf < 4; ++nf) {
        int col = wv * 64 + nf * 16 + frow;
        float bb = b2[col];
#pragma unroll
        for (int mf = 0; mf < 2; ++mf) {
#pragma unroll
            for (int j = 0; j < 4; ++j) {
                int gr = rowBase + mf * 16 + kg * 4 + j;
                if (gr < M) HP[(size_t)gr * DD + col] = f2h(acc2[mf][nf][j] + bb);
            }
        }
    }
}

// ---------------- fully fused GRU kernel (R11-verified, 222 us) ----------------
template <bool FINAL>
__global__ __launch_bounds__(512, 2)
void gru_fused(const u16* __restrict__ pMsg, const u16* __restrict__ pX, size_t psA,
               const u16* __restrict__ pWih, const u16* __restrict__ pWhh, size_t psB,
               const float* __restrict__ bih, const float* __restrict__ bhh,
               float* __restrict__ outF, u16* __restrict__ outP, size_t psO, int M) {
    // LDS (u16): A 2 planes x [128][32] at 0/4096 (16 KB);
    // B panel g (g=0,1,2) at 8192+g*8192: hi, +4096 lo (48 KB). Total 64 KB.
    __shared__ u16 lds[32768];

    const int tid = threadIdx.x;
    const int lane = tid & 63;
    const int wv = tid >> 6;           // 0..7
    const int wr = wv >> 2;            // 0..1 (64-row half)
    const int wc = wv & 3;             // 0..3 (32-col quarter)
    const int frow = lane & 15;
    const int kg = lane >> 4;
    const int rowBase = blockIdx.x * BM;
    const int colBase = blockIdx.y * BN;

    int offj[8]; int ldsj[8]; bool isBj[8];
#pragma unroll
    for (int j = 0; j < 8; ++j) {
        int q = wv * 8 + j;
        bool isB = q >= 16;
        int eoff, ldso;
        if (!isB) {
            int p = (q >> 3) & 1; int sub = q & 7;
            int row = sub * 16 + (lane >> 2);
            int chunk = (lane & 3) ^ ((row >> 1) & 3);
            eoff = p * (int)psA + (rowBase + row) * DD + chunk * 8;
            ldso = q * 512;
        } else {
            int qb = q - 16;                 // 0..47
            int g = qb >> 4;                 // panel (gate) 0..2
            int p = (qb >> 3) & 1; int sub = qb & 7;
            int row = sub * 16 + (lane >> 2);
            int chunk = (lane & 3) ^ ((row >> 1) & 3);
            eoff = p * (int)psB + (g * 256 + colBase + row) * DD + chunk * 8;
            ldso = 8192 + qb * 512;
        }
        offj[j] = eoff; ldsj[j] = ldso; isBj[j] = isB;
    }

    f32x4 accr[4][2] = {};
    f32x4 accz[4][2] = {};
    f32x4 accx[4][2] = {};
    f32x4 acch[4][2] = {};

#pragma unroll
    for (int half = 0; half < 2; ++half) {
        const u16* Ab = half ? pX : pMsg;
        const u16* Bb = half ? pWhh : pWih;
        for (int kc = 0; kc < DD; kc += BK) {
#pragma unroll
            for (int j = 0; j < 8; ++j)
                gload16((isBj[j] ? Bb : Ab) + offj[j] + kc, &lds[ldsj[j]]);
            __syncthreads();

            f16x8 af[2][4];
#pragma unroll
            for (int mf = 0; mf < 4; ++mf) {
                int row = wr * 64 + mf * 16 + frow;
                int off = row * 32 + ((kg ^ ((row >> 1) & 3)) * 8);
                af[0][mf] = *reinterpret_cast<const f16x8*>(&lds[off]);
                af[1][mf] = *reinterpret_cast<const f16x8*>(&lds[4096 + off]);
            }
#pragma unroll
            for (int g = 0; g < 3; ++g) {
#pragma unroll
                for (int nf = 0; nf < 2; ++nf) {
                    int brow = wc * 32 + nf * 16 + frow;
                    int boff = 8192 + g * 8192 + brow * 32 + ((kg ^ ((brow >> 1) & 3)) * 8);
                    f16x8 bh = *reinterpret_cast<const f16x8*>(&lds[boff]);
                    f16x8 bl = *reinterpret_cast<const f16x8*>(&lds[boff + 4096]);
#pragma unroll
                    for (int mf = 0; mf < 4; ++mf) {
                        f32x4 c = (g == 0) ? accr[mf][nf]
                                : (g == 1) ? accz[mf][nf]
                                : (half == 0) ? accx[mf][nf] : acch[mf][nf];
                        c = __builtin_amdgcn_mfma_f32_16x16x32_f16(af[0][mf], bh, c, 0, 0, 0);
                        c = __builtin_amdgcn_mfma_f32_16x16x32_f16(af[0][mf], bl, c, 0, 0, 0);
                        c = __builtin_amdgcn_mfma_f32_16x16x32_f16(af[1][mf], bh, c, 0, 0, 0);
                        if (g == 0)      accr[mf][nf] = c;
                        else if (g == 1) accz[mf][nf] = c;
                        else if (half == 0) accx[mf][nf] = c;
                        else                acch[mf][nf] = c;
                    }
                }
            }
            __syncthreads();
        }
    }

    // epilogue: full GRU update
#pragma unroll
    for (int nf = 0; nf < 2; ++nf) {
        int gc = colBase + wc * 32 + nf * 16 + frow;
        float br = bih[gc] + bhh[gc];
        float bz = bih[256 + gc] + bhh[256 + gc];
        float bx = bih[512 + gc];
        float bh = bhh[512 + gc];
#pragma unroll
        for (int mf = 0; mf < 4; ++mf) {
#pragma unroll
            for (int j = 0; j < 4; ++j) {
                int gr = rowBase + wr * 64 + mf * 16 + kg * 4 + j;
                if (gr < M) {
                    size_t off = (size_t)gr * DD + gc;
                    float r = sigmoidf_(accr[mf][nf][j] + br);
                    float z = sigmoidf_(accz[mf][nf][j] + bz);
                    float T = tanhf(accx[mf][nf][j] + bx + r * (acch[mf][nf][j] + bh));
                    float x = h2f(pX[off]) + h2f(pX[psA + off]);
                    float o = (1.0f - z) * T + z * x;
                    if (FINAL) outF[off] = o;
                    else       store_planes(outP, psO, off, o);
                }
            }
        }
    }
}

// ---------------- segment sum (gather over fp16 h table) -> msg planes ----------------
__global__ __launch_bounds__(256)
void segsum_kernel(const u16* __restrict__ hp, const int* __restrict__ row_ptr,
                   const int* __restrict__ csr_src, u16* __restrict__ msgP,
                   size_t ps, int n) {
    int node = blockIdx.x * 4 + threadIdx.y;
    if (node >= n) return;
    int d4 = threadIdx.x * 4;
    int s = row_ptr[node];
    int e = row_ptr[node + 1];
    float4 acc = make_float4(0.f, 0.f, 0.f, 0.f);
    for (int j = s; j < e; ++j) {
        int sn = csr_src[j];
        f16x4 v = *reinterpret_cast<const f16x4*>(&hp[(size_t)sn * DD + d4]);
        acc.x += (float)v[0]; acc.y += (float)v[1];
        acc.z += (float)v[2]; acc.w += (float)v[3];
    }
    size_t off = (size_t)node * DD + d4;
    u16 h0,l0,h1,l1,h2,l2,h3,l3;
    split2(acc.x, h0,l0); split2(acc.y, h1,l1);
    split2(acc.z, h2,l2); split2(acc.w, h3,l3);
    *reinterpret_cast<uint2*>(&msgP[off])      = make_uint2(pk(h0,h1), pk(h2,h3));
    *reinterpret_cast<uint2*>(&msgP[ps + off]) = make_uint2(pk(l0,l1), pk(l2,l3));
}

// ---------------- launch ----------------

extern "C" void kernel_launch(void* const* d_in, const int* in_sizes, int n_in,
                              void* d_out, int out_size, void* d_ws, size_t ws_size,
                              hipStream_t stream) {
    const float* x0  = (const float*)d_in[0];
    const float* W1  = (const float*)d_in[1];
    const float* b1  = (const float*)d_in[2];
    const float* W2  = (const float*)d_in[3];
    const float* b2  = (const float*)d_in[4];
    const float* Wih = (const float*)d_in[5];
    const float* bih = (const float*)d_in[6];
    const float* Whh = (const float*)d_in[7];
    const float* bhh = (const float*)d_in[8];
    const int*   src = (const int*)d_in[9];
    const int*   dst = (const int*)d_in[10];

    // workspace layout (~211.3 MB — proven footprint)
    char* ws = (char*)d_ws;
    const size_t PSA = (size_t)NNP * DD;              // elems per activation plane
    const size_t SP  = PSA * 2 * sizeof(u16);         // 51.25 MB (2 fp16 planes)
    const size_t NB  = PSA * sizeof(float);           // 51.25 MB
    const size_t PSW2 = (size_t)DD * DD;              // 65536
    const size_t PSW3 = (size_t)3 * DD * DD;          // 196608
    u16* XP0   = (u16*)(ws);                          // x planes (even steps)
    u16* XP1   = (u16*)(ws + SP);                     // x planes (odd steps)
    u16* TP    = (u16*)(ws + 2 * SP);                 // msg planes
    u16* HP    = (u16*)(ws + 3 * SP);                 // h fp16 plane
    u16* W1P   = (u16*)(ws + 3 * SP + NB);
    u16* W2P   = W1P + 2 * PSW2;
    u16* WIHP  = W2P + 2 * PSW2;
    u16* WHHP  = WIHP + 2 * PSW3;
    int* counts  = (int*)(WHHP + 2 * PSW3);
    int* cursor  = counts + NN;
    int* row_ptr = cursor + NN;                       // NN+1 ints
    int* csr     = row_ptr + NN + 8;                  // NE ints
    const size_t needed = 3 * SP + NB + (4 * PSW2 + 4 * PSW3) * sizeof(u16)
                        + (size_t)(2 * NN + NN + 9 + NE) * sizeof(int);
    if (ws_size < needed) return;   // clean fail instead of OOB crash

    float* FOUT = (float*)d_out;

    // CSR build
    zero_kernel<<<(2 * NN + 255) / 256, 256, 0, stream>>>(counts, 2 * NN);
    hist_kernel<<<(NE + 255) / 256, 256, 0, stream>>>(dst, counts, NE);
    scan_kernel<<<1, 1024, 0, stream>>>(counts, row_ptr, NN);
    fill_kernel<<<(NE + 255) / 256, 256, 0, stream>>>(src, dst, row_ptr, cursor, csr, NE);

    // pre-split weights (once) and x0 -> XP0
    split_rows<<<DD, 256, 0, stream>>>(W1, W1P, PSW2, DD);
    split_rows<<<DD, 256, 0, stream>>>(W2, W2P, PSW2, DD);
    split_rows<<<3 * DD, 256, 0, stream>>>(Wih, WIHP, PSW3, 3 * DD);
    split_rows<<<3 * DD, 256, 0, stream>>>(Whh, WHHP, PSW3, 3 * DD);
    split_rows<<<NNP, 256, 0, stream>>>(x0, XP0, PSA, NN);

    const dim3 grid(NNP / BM, DD / BN);   // 391 x 2 (gru_fused)

    for (int s = 0; s < NSTEPS; ++s) {
        u16* XPc = (s & 1) ? XP1 : XP0;
        u16* XPn = (s & 1) ? XP0 : XP1;

        // h = MLP(x) -> HP (single fp16 plane), t1 never touches HBM
        mlp_fused<<<NNP / 32, 256, 0, stream>>>(
            XPc, PSA, W1P, W2P, PSW2, b1, b2, HP, NN);
        // msg = segment_sum(h[src], dst) -> TP planes
        segsum_kernel<<<dim3((NN + 3) / 4), dim3(64, 4), 0, stream>>>(
            HP, row_ptr, csr, TP, PSA, NN);
        // full GRU update in one kernel -> x_next planes (final: fp32 d_out)
        if (s < NSTEPS - 1) {
            gru_fused<false><<<grid, 512, 0, stream>>>(
                TP, XPc, PSA, WIHP, WHHP, PSW3, bih, bhh,
                nullptr, XPn, PSA, NN);
        } else {
            gru_fused<true><<<grid, 512, 0, stream>>>(
                TP, XPc, PSA, WIHP, WHHP, PSW3, bih, bhh,
                FOUT, nullptr, 0, NN);
        }
    }
}